// Round 8
// baseline (1508.882 us; speedup 1.0000x reference)
//
#include <hip/hip_runtime.h>
#include <stdint.h>
#include <math.h>

#define B_    2048
#define DIN_  512
#define H_    768
#define G3_   2304          // 3*H
#define A_    5001
#define APAD_ 5120
#define RL_   4
#define NDATA_ 56000.0f

typedef _Float16 f16x8 __attribute__((ext_vector_type(8)));
typedef _Float16 f16x4 __attribute__((ext_vector_type(4)));
typedef float    f32x4 __attribute__((ext_vector_type(4)));

// ---------------- threefry2x32 (exact JAX semantics) ----------------
__host__ __device__ __forceinline__ void threefry2x32(
    uint32_t k0, uint32_t k1, uint32_t x0, uint32_t x1,
    uint32_t* o0, uint32_t* o1)
{
  const uint32_t ks2 = k0 ^ k1 ^ 0x1BD11BDAu;
#define TF_R(r) { x0 += x1; x1 = (x1 << (r)) | (x1 >> (32 - (r))); x1 ^= x0; }
  x0 += k0; x1 += k1;
  TF_R(13) TF_R(15) TF_R(26) TF_R(6)
  x0 += k1;  x1 += ks2 + 1u;
  TF_R(17) TF_R(29) TF_R(16) TF_R(24)
  x0 += ks2; x1 += k0 + 2u;
  TF_R(13) TF_R(15) TF_R(26) TF_R(6)
  x0 += k0;  x1 += k1 + 3u;
  TF_R(17) TF_R(29) TF_R(16) TF_R(24)
  x0 += k1;  x1 += ks2 + 4u;
  TF_R(13) TF_R(15) TF_R(26) TF_R(6)
  x0 += ks2; x1 += k0 + 5u;
#undef TF_R
  *o0 = x0; *o1 = x1;
}

__device__ __forceinline__ float gumbel_for(uint32_t k0, uint32_t k1, uint32_t n)
{
  uint32_t o0, o1;
  threefry2x32(k0, k1, 0u, n, &o0, &o1);
  const uint32_t bits = o0 ^ o1;
  const float f = __uint_as_float((bits >> 9) | 0x3f800000u);  // [1,2)
  const float minv = 1e-6f;
  const float maxv = 1.0f - 1e-6f;
  const float span = maxv - minv;
  float u = __fmul_rn(f, span);
  u = __fadd_rn(u, minv);
  u = __fsub_rn(u, span);
  u = fmaxf(minv, u);
  return -logf(-logf(u));
}

// split v*64 into f16 hi/lo
struct HL { _Float16 h, l; };
__device__ __forceinline__ HL split64(float v)
{
  HL r;
  const float s = v * 64.f;
  r.h = (_Float16)s;
  r.l = (_Float16)(s - (float)r.h);
  return r;
}

// ---------------- merged pre-split of 7 weight tensors ----------------
struct PSJobs {
  const float* src[7];
  _Float16* hi[7];
  _Float16* lo[7];
  int R[7]; int K[7];
  int cum[8];          // cumulative float4 counts
};

__global__ __launch_bounds__(256)
void presplit_all(PSJobs J)
{
  const int g = blockIdx.x * 256 + threadIdx.x;
  if (g >= J.cum[7]) return;
  int j = 0;
  while (g >= J.cum[j + 1]) ++j;
  const int i = g - J.cum[j];
  const int K = J.K[j];
  const int e = i * 4;
  const int row = e / K;
  float4 f = make_float4(0.f, 0.f, 0.f, 0.f);
  if (row < J.R[j]) f = *(const float4*)(J.src[j] + (size_t)row * K + (e - row * K));
  const HL s0 = split64(f.x), s1 = split64(f.y);
  const HL s2 = split64(f.z), s3 = split64(f.w);
  const f16x4 hv = {s0.h, s1.h, s2.h, s3.h};
  ((f16x4*)J.hi[j])[i] = hv;
  if (J.lo[j]) {
    const f16x4 lv = {s0.l, s1.l, s2.l, s3.l};
    ((f16x4*)J.lo[j])[i] = lv;
  }
}

// ---------------- combined prep: mask init + max||Wh_a||^2 + x split ------
__global__ __launch_bounds__(256)
void prep_k(const int* __restrict__ xmask, uint8_t* __restrict__ mask,
            const float* __restrict__ Wh, float* __restrict__ wmaxsq,
            const float* __restrict__ x, _Float16* __restrict__ xh,
            _Float16* __restrict__ xl)
{
  const int blk = blockIdx.x, tid = threadIdx.x;
  __shared__ float redf[256];
  __shared__ int   redi[256];
  if (blk < B_) {                       // mask init (+ step-0 row_zero fix)
    const int b = blk;
    int s = 0;
    for (int a = tid; a < A_; a += 256) {
      const int m = (xmask[(size_t)b * A_ + a] != 0) ? 1 : 0;
      mask[(size_t)b * A_ + a] = (uint8_t)m;
      s += m;
    }
    redi[tid] = s; __syncthreads();
    for (int t = 128; t > 0; t >>= 1) {
      if (tid < t) redi[tid] += redi[tid + t];
      __syncthreads();
    }
    if (tid == 0 && redi[0] == 0) mask[(size_t)b * A_] = 1;
  } else if (blk < B_ + A_) {           // max row-norm^2 of Wh
    const int a = blk - B_;
    float p = 0.f;
    for (int d = tid; d < H_; d += 256) {
      const float w = Wh[(size_t)a * H_ + d];
      p += w * w;
    }
    redf[tid] = p; __syncthreads();
    for (int t = 128; t > 0; t >>= 1) {
      if (tid < t) redf[tid] += redf[tid + t];
      __syncthreads();
    }
    if (tid == 0) atomicMax((int*)wmaxsq, __float_as_int(redf[0]));
  } else {                              // split x
    const int i = (blk - B_ - A_) * 256 + tid;
    const int n4 = B_ * DIN_ / 4;
    if (i < n4) {
      const float4 f = ((const float4*)x)[i];
      const HL s0 = split64(f.x), s1 = split64(f.y);
      const HL s2 = split64(f.z), s3 = split64(f.w);
      const f16x4 hv = {s0.h, s1.h, s2.h, s3.h};
      const f16x4 lv = {s0.l, s1.l, s2.l, s3.l};
      ((f16x4*)xh)[i] = hv;
      ((f16x4*)xl)[i] = lv;
    }
  }
}

// ================= barrier-free direct-global f16-split MFMA GEMM ==========
// Job: C[m, n0+n] = A[m,:] @ B[n0+n,:] + bias.  npass=3: hihi+lohi+hilo.
// No LDS: fragments load straight global->VGPR (16B/lane, whole 64B lines).
// hi-frags double-buffered in regs (prefetch t+1 before MFMA t); lo single.
struct GJob {
  const _Float16 *Ah, *Al, *Bh, *Bl;
  const float* bias;
  float* C;
  _Float16 *Ch, *Cl;
  int M, K, ldc, n0, Nv;   // store iff n_global < Nv; offset m*ldc + n_global
  int npass, act, wsplit, gum;
};
struct GArgs { GJob j[2]; int sx; uint32_t k0, k1; };

__global__ __launch_bounds__(256)
void gemm2job(GArgs P)
{
  const int jid = (blockIdx.x < P.sx) ? 0 : 1;
  const GJob J = P.j[jid];
  const int bxx = blockIdx.x - (jid ? P.sx : 0);
  const int bm = blockIdx.y * 128;
  if (bm >= J.M) return;
  const int bn = J.n0 + bxx * 128;

  const int tid = threadIdx.x;
  const int lane = tid & 63, wave = tid >> 6;
  const int wx = wave & 1, wy = wave >> 1;
  const int q = lane >> 4, mr = lane & 15;
  const int K = J.K;
  const int np3 = (J.npass == 3);
  // lo planes at a uniform (SGPR) element delta from hi
  const ptrdiff_t dA = np3 ? (J.Al - J.Ah) : 0;
  const ptrdiff_t dB = np3 ? (J.Bl - J.Bh) : 0;

  const _Float16 *pa[4], *pb[4];
#pragma unroll
  for (int i = 0; i < 4; ++i) {
    pa[i] = J.Ah + (size_t)(bm + wy * 64 + i * 16 + mr) * K + q * 8;
    pb[i] = J.Bh + (size_t)(bn + wx * 64 + i * 16 + mr) * K + q * 8;
  }

  f32x4 acc[4][4];
#pragma unroll
  for (int i = 0; i < 4; ++i)
#pragma unroll
    for (int j = 0; j < 4; ++j) acc[i][j] = (f32x4)0.f;

  const int T = K / 32;
  f16x8 a0[4], b0[4], a1[4], b1[4], la[4], lb[4];

#pragma unroll
  for (int i = 0; i < 4; ++i) {
    a0[i] = *(const f16x8*)(pa[i]);
    b0[i] = *(const f16x8*)(pb[i]);
  }

  auto kstep = [&](int t, f16x8* ac, f16x8* bc, f16x8* an, f16x8* bn2) {
    const int o = t * 32;
    if (np3) {
#pragma unroll
      for (int i = 0; i < 4; ++i) {
        la[i] = *(const f16x8*)(pa[i] + o + dA);
        lb[i] = *(const f16x8*)(pb[i] + o + dB);
      }
    }
    if (t + 1 < T) {
      const int o1 = o + 32;
#pragma unroll
      for (int i = 0; i < 4; ++i) {
        an[i]  = *(const f16x8*)(pa[i] + o1);
        bn2[i] = *(const f16x8*)(pb[i] + o1);
      }
    }
#pragma unroll
    for (int ni = 0; ni < 4; ++ni)
#pragma unroll
      for (int mi = 0; mi < 4; ++mi)
        acc[mi][ni] = __builtin_amdgcn_mfma_f32_16x16x32_f16(ac[mi], bc[ni], acc[mi][ni], 0, 0, 0);
    if (np3) {
#pragma unroll
      for (int ni = 0; ni < 4; ++ni)
#pragma unroll
        for (int mi = 0; mi < 4; ++mi) {
          acc[mi][ni] = __builtin_amdgcn_mfma_f32_16x16x32_f16(la[mi], bc[ni], acc[mi][ni], 0, 0, 0);
          acc[mi][ni] = __builtin_amdgcn_mfma_f32_16x16x32_f16(ac[mi], lb[ni], acc[mi][ni], 0, 0, 0);
        }
    }
  };

  for (int t = 0; t < T; t += 2) {
    kstep(t, a0, b0, a1, b1);
    if (t + 1 < T) kstep(t + 1, a1, b1, a0, b0);
  }

  // epilogue: C/D layout col=lane&15, row=(lane>>4)*4+reg
  const float sc = 1.f / 4096.f;
#pragma unroll
  for (int ni = 0; ni < 4; ++ni) {
    const int n = bn + wx * 64 + ni * 16 + mr;
    if (n >= J.Nv) continue;
    const float bv = J.bias ? J.bias[n] : 0.f;
#pragma unroll
    for (int mi = 0; mi < 4; ++mi) {
      const int m0 = bm + wy * 64 + mi * 16 + q * 4;
#pragma unroll
      for (int r = 0; r < 4; ++r) {
        const int m = m0 + r;
        float v = acc[mi][ni][r] * sc + bv;
        if (J.act) v = fmaxf(v, 0.f);
        if (J.gum) v += gumbel_for(P.k0, P.k1, (uint32_t)(m * J.ldc + n));
        const size_t off = (size_t)m * J.ldc + n;
        if (J.C) J.C[off] = v;
        if (J.wsplit) {
          const HL s = split64(v);
          J.Ch[off] = s.h;
          J.Cl[off] = s.l;
        }
      }
    }
  }
}

// ---------------- GRU elementwise (step 0 only) + fused h split ----------
__global__ __launch_bounds__(256)
void gru_elem(const float* __restrict__ gi, const float* __restrict__ bhh,
              float* __restrict__ h, _Float16* __restrict__ hh_,
              _Float16* __restrict__ hl_)
{
  const int i = blockIdx.x * 256 + threadIdx.x;
  if (i >= B_ * H_) return;
  const int b = i / H_;
  const int d = i - b * H_;
  const float* gib = gi + (size_t)b * G3_;
  const float ir = gib[d], iz = gib[H_ + d], in_ = gib[2 * H_ + d];
  const float hr = bhh[d], hz = bhh[H_ + d], hn = bhh[2 * H_ + d];
  const float r = 1.f / (1.f + expf(-(ir + hr)));
  const float z = 1.f / (1.f + expf(-(iz + hz)));
  const float n = tanhf(in_ + r * hn);
  const float hv = (1.f - z) * n;      // h_prev = 0
  h[i] = hv;
  const HL s = split64(hv);
  hh_[i] = s.h; hl_[i] = s.l;
}

// ---------------- select + fused GRU for the next step --------------------
__global__ __launch_bounds__(256)
void select_step(const float* __restrict__ v, uint8_t* __restrict__ mask,
                 int* __restrict__ idxs, const float* __restrict__ giCls,
                 const float* __restrict__ AeWih, float* __restrict__ atomp,
                 float* __restrict__ hbuf, const float* __restrict__ WhF,
                 const float* __restrict__ bh, const float* __restrict__ wmaxsq,
                 const float* __restrict__ gh, const float* __restrict__ bhh,
                 _Float16* __restrict__ hh_, _Float16* __restrict__ hl_,
                 uint32_t k0, uint32_t k1, int step)
{
  const int b = blockIdx.x, tid = threadIdx.x;
  uint8_t* mrow = mask + (size_t)b * A_;
  __shared__ float vsh[A_];        // masked v row cache (20 KB)
  __shared__ float hsh[H_];
  __shared__ float gish[G3_];
  __shared__ float sv[256];
  __shared__ int   si[256];
  __shared__ int   s_list[64];
  __shared__ int   s_n;
  __shared__ int   s_sel;

  // h_j row -> LDS + ||h||^2
  float hp = 0.f;
  for (int d = tid; d < H_; d += 256) {
    const float t = hbuf[(size_t)b * H_ + d];
    hsh[d] = t; hp += t * t;
  }
  sv[tid] = hp; __syncthreads();
  for (int t = 128; t > 0; t >>= 1) {
    if (tid < t) sv[tid] += sv[tid + t];
    __syncthreads();
  }
  const float hn2 = sv[0];
  __syncthreads();

  // mask update
  if (step > 0) {
    const int prev = idxs[(step - 1) * B_ + b];
    if (prev == 0)
      for (int a = tid; a < A_; a += 256) mrow[a] = 0;
    __syncthreads();
    if (tid == 0) mrow[0] = 1;
  }
  if (tid == 0) s_n = 0;
  __syncthreads();

  // single pass: mask-apply, cache in LDS, track max
  const float* vrow = v + (size_t)b * A_;
  float bv = -INFINITY; int bi = A_;
  for (int a = tid; a < A_; a += 256) {
    const float val = mrow[a] ? vrow[a] : -INFINITY;
    vsh[a] = val;
    if (val > bv) { bv = val; bi = a; }
  }
  sv[tid] = bv; si[tid] = bi; __syncthreads();
  for (int t = 128; t > 0; t >>= 1) {
    if (tid < t) {
      const float v2 = sv[tid + t]; const int i2 = si[tid + t];
      if (v2 > sv[tid] || (v2 == sv[tid] && i2 < si[tid])) { sv[tid] = v2; si[tid] = i2; }
    }
    __syncthreads();
  }
  const float amax = sv[0];
  __syncthreads();

  // |approx-exact| <= 2^-10 * ||h|| * max||w_a||  (x2 safety)
  const float delta = 2.0f * 0.0009765625f * sqrtf(hn2 * wmaxsq[0]);
  const float thr = amax - 2.f * delta;

  for (int a = tid; a < A_; a += 256)
    if (vsh[a] >= thr) {
      const int p = atomicAdd(&s_n, 1);
      if (p < 64) s_list[p] = a;
    }
  __syncthreads();
  const int nc = (s_n < 64) ? s_n : 64;

  // exact fp32 re-eval; argmax with lowest-index tie-break
  const uint32_t nbase = (uint32_t)b * (uint32_t)A_;
  float best = -INFINITY; int bestA = A_;
  for (int c = 0; c < nc; ++c) {
    const int a = s_list[c];
    const float* wr = WhF + (size_t)a * H_;
    float p = 0.f;
    for (int d = tid; d < H_; d += 256) p += hsh[d] * wr[d];
    sv[tid] = p; __syncthreads();
    for (int t = 128; t > 0; t >>= 1) {
      if (tid < t) sv[tid] += sv[tid + t];
      __syncthreads();
    }
    if (tid == 0) {
      const float ev = sv[0] + bh[a] + gumbel_for(k0, k1, nbase + (uint32_t)a);
      if (ev > best || (ev == best && a < bestA)) { best = ev; bestA = a; }
    }
    __syncthreads();
  }
  if (tid == 0) {
    s_sel = bestA;
    mrow[bestA] = 0;
    idxs[step * B_ + b] = bestA;
    atomp[(size_t)b * (RL_ * A_) + (size_t)step * A_ + bestA] = 1.0f;
  }
  __syncthreads();

  if (step < RL_ - 1) {
    // gi_{j+1} row = giCls + AeWih[sel]  (LDS), then fused GRU -> h_{j+1}
    const int sel = s_sel;
    const float* ar = AeWih + (size_t)sel * G3_;
    const float* gr = giCls + (size_t)b * G3_;
    for (int d = tid; d < G3_; d += 256) gish[d] = gr[d] + ar[d];
    __syncthreads();
    const float* ghb = gh + (size_t)b * G3_;
    for (int d = tid; d < H_; d += 256) {
      const float r = 1.f / (1.f + expf(-(gish[d] + ghb[d])));
      const float z = 1.f / (1.f + expf(-(gish[H_ + d] + ghb[H_ + d])));
      const float n = tanhf(gish[2 * H_ + d] + r * ghb[2 * H_ + d]);
      const float hv = (1.f - z) * n + z * hsh[d];
      hbuf[(size_t)b * H_ + d] = hv;
      const HL s = split64(hv);
      hh_[(size_t)b * H_ + d] = s.h;
      hl_[(size_t)b * H_ + d] = s.l;
    }
  }
}

// ---------------- final heads ----------------
__global__ __launch_bounds__(256)
void head_k(const int* __restrict__ idxs, const float* __restrict__ ae,
            const float* __restrict__ w_mu, const float* __restrict__ b_mu,
            const float* __restrict__ w_cov, const float* __restrict__ b_cov,
            const float* __restrict__ alpha, float* __restrict__ outf)
{
  const int b = blockIdx.x, tid = threadIdx.x;
  const int i0 = idxs[0 * B_ + b], i1 = idxs[1 * B_ + b];
  const int i2 = idxs[2 * B_ + b], i3 = idxs[3 * B_ + b];
  const float* r0 = ae + (size_t)i0 * H_;
  const float* r1 = ae + (size_t)i1 * H_;
  const float* r2 = ae + (size_t)i2 * H_;
  const float* r3 = ae + (size_t)i3 * H_;
  float pmu = 0.f, pcv = 0.f;
  for (int d = tid; d < H_; d += 256) {
    const float a = r0[d] + r1[d] + r2[d] + r3[d];
    pmu += a * w_mu[d];
    pcv += a * w_cov[d];
  }
  __shared__ float smu[256], scv[256];
  smu[tid] = pmu; scv[tid] = pcv;
  __syncthreads();
  for (int s = 128; s > 0; s >>= 1) {
    if (tid < s) { smu[tid] += smu[tid + s]; scv[tid] += scv[tid + s]; }
    __syncthreads();
  }
  if (tid == 0) {
    const float mu = 1.f / (1.f + expf(-(smu[0] + b_mu[0])));
    const float cv = 1.f / (1.f + expf(-(scv[0] + b_cov[0])));
    const float n = cv * NDATA_;
    const float inv = alpha[0] / n;
    const float pp = (mu + inv) / (1.f + 2.f * inv);
    outf[2 * b + 0] = logf(1.f - pp);
    outf[2 * b + 1] = logf(pp);
    float* cp = outf + 2 * B_ + (size_t)B_ * RL_ * A_;
    cp[2 * b + 0] = 1.f - pp;
    cp[2 * b + 1] = pp;
  }
}

// ---------------- launch ----------------
extern "C" void kernel_launch(void* const* d_in, const int* in_sizes, int n_in,
                              void* d_out, int out_size, void* d_ws, size_t ws_size,
                              hipStream_t stream)
{
  const float* x     = (const float*)d_in[0];
  const int*   xmask = (const int*)d_in[1];
  const float* W1 = (const float*)d_in[2];  const float* b1 = (const float*)d_in[3];
  const float* W2 = (const float*)d_in[4];  const float* b2 = (const float*)d_in[5];
  const float* W3 = (const float*)d_in[6];  const float* b3 = (const float*)d_in[7];
  const float* Wih = (const float*)d_in[8]; const float* bih = (const float*)d_in[9];
  const float* Whh = (const float*)d_in[10];const float* bhh = (const float*)d_in[11];
  const float* Wh = (const float*)d_in[12]; const float* bh = (const float*)d_in[13];
  const float* ae = (const float*)d_in[14];
  const float* w_mu = (const float*)d_in[15];  const float* b_mu = (const float*)d_in[16];
  const float* w_cov = (const float*)d_in[17]; const float* b_cov = (const float*)d_in[18];
  const float* alpha = (const float*)d_in[19];

  char* ws = (char*)d_ws;
  size_t off = 0;
  auto alloc = [&](size_t bytes) -> void* {
    void* p = ws + off;
    off += (bytes + 255) & ~(size_t)255;
    return p;
  };
  float* hbuf   = (float*)alloc((size_t)B_ * H_ * 4);
  float* giCls  = (float*)alloc((size_t)B_ * G3_ * 4);
  float* gh     = (float*)alloc((size_t)B_ * G3_ * 4);
  float* vbuf   = (float*)alloc((size_t)B_ * A_ * 4);
  float* AeWih  = (float*)alloc((size_t)APAD_ * G3_ * 4);
  uint8_t* mask = (uint8_t*)alloc((size_t)B_ * A_);
  int* idxs     = (int*)alloc((size_t)RL_ * B_ * 4);
  _Float16* hh_ = (_Float16*)alloc((size_t)B_ * H_ * 2);
  _Float16* hl_ = (_Float16*)alloc((size_t)B_ * H_ * 2);
  _Float16* clsh = (_Float16*)alloc((size_t)B_ * H_ * 2);
  _Float16* clsl = (_Float16*)alloc((size_t)B_ * H_ * 2);
  _Float16* xh  = (_Float16*)alloc((size_t)B_ * DIN_ * 2);
  _Float16* xl  = (_Float16*)alloc((size_t)B_ * DIN_ * 2);
  _Float16* t1h = (_Float16*)alloc((size_t)B_ * H_ * 2);
  _Float16* t1l = (_Float16*)alloc((size_t)B_ * H_ * 2);
  _Float16* t2h = (_Float16*)alloc((size_t)B_ * H_ * 2);
  _Float16* t2l = (_Float16*)alloc((size_t)B_ * H_ * 2);
  _Float16* w1h = (_Float16*)alloc((size_t)H_ * DIN_ * 2);
  _Float16* w1l = (_Float16*)alloc((size_t)H_ * DIN_ * 2);
  _Float16* w2h = (_Float16*)alloc((size_t)H_ * H_ * 2);
  _Float16* w2l = (_Float16*)alloc((size_t)H_ * H_ * 2);
  _Float16* w3h = (_Float16*)alloc((size_t)H_ * H_ * 2);
  _Float16* w3l = (_Float16*)alloc((size_t)H_ * H_ * 2);
  _Float16* wihh = (_Float16*)alloc((size_t)G3_ * H_ * 2);
  _Float16* wihl = (_Float16*)alloc((size_t)G3_ * H_ * 2);
  _Float16* whhh = (_Float16*)alloc((size_t)G3_ * H_ * 2);
  _Float16* whhl = (_Float16*)alloc((size_t)G3_ * H_ * 2);
  _Float16* whhi = (_Float16*)alloc((size_t)APAD_ * H_ * 2);  // Wh hi (1-pass)
  _Float16* aeh  = (_Float16*)alloc((size_t)APAD_ * H_ * 2);
  _Float16* ael  = (_Float16*)alloc((size_t)APAD_ * H_ * 2);
  float* wmaxsq = (float*)alloc(4);

  float* outf  = (float*)d_out;
  float* atomp = outf + 2 * B_;

  (void)hipMemsetAsync(d_out, 0, (size_t)out_size * sizeof(float), stream);
  (void)hipMemsetAsync(wmaxsq, 0, 4, stream);

  // merged presplit: W1 W2 W3 Wih Whh Wh(hi) ae(hi+lo)
  PSJobs J;
  const float* srcs[7] = {W1, W2, W3, Wih, Whh, Wh, ae};
  _Float16* his[7] = {w1h, w2h, w3h, wihh, whhh, whhi, aeh};
  _Float16* los[7] = {w1l, w2l, w3l, wihl, whhl, nullptr, ael};
  const int Rs[7]    = {H_, H_, H_, G3_, G3_, A_, A_};
  const int Rpads[7] = {H_, H_, H_, G3_, G3_, APAD_, APAD_};
  const int Ks[7]    = {DIN_, H_, H_, H_, H_, H_, H_};
  J.cum[0] = 0;
  for (int j = 0; j < 7; ++j) {
    J.src[j] = srcs[j]; J.hi[j] = his[j]; J.lo[j] = los[j];
    J.R[j] = Rs[j]; J.K[j] = Ks[j];
    J.cum[j + 1] = J.cum[j] + Rpads[j] * Ks[j] / 4;
  }
  presplit_all<<<(J.cum[7] + 255) / 256, 256, 0, stream>>>(J);

  prep_k<<<B_ + A_ + (B_ * DIN_ / 4 + 255) / 256, 256, 0, stream>>>(
      xmask, mask, Wh, wmaxsq, x, xh, xl);

  auto mkjob = [](const _Float16* Ah, const _Float16* Al, const _Float16* Bh,
                  const _Float16* Bl, const float* bias, float* C,
                  _Float16* Ch, _Float16* Cl, int M, int K, int ldc,
                  int n0, int Nv, int npass, int act, int wsplit, int gum) {
    GJob g; g.Ah = Ah; g.Al = Al; g.Bh = Bh; g.Bl = Bl; g.bias = bias;
    g.C = C; g.Ch = Ch; g.Cl = Cl; g.M = M; g.K = K; g.ldc = ldc;
    g.n0 = n0; g.Nv = Nv; g.npass = npass; g.act = act; g.wsplit = wsplit;
    g.gum = gum;
    return g;
  };
  auto aejob = [&](int t0) {   // AeWih column-chunk job
    return mkjob(aeh, ael, wihh, wihl, nullptr, AeWih, nullptr, nullptr,
                 APAD_, H_, G3_, t0 * 128, G3_, 3, 0, 0, 0);
  };

  // MLP chain with AeWih column chunks (5,5,4,4 tiles) as concurrent filler
  {
    GArgs P;
    P.j[0] = mkjob(xh, xl, w1h, w1l, b1, nullptr, t1h, t1l,
                   B_, DIN_, H_, 0, H_, 3, 1, 1, 0);
    P.j[1] = aejob(0);
    P.sx = H_ / 128; P.k0 = 0; P.k1 = 0;
    gemm2job<<<dim3(H_ / 128 + 5, APAD_ / 128), 256, 0, stream>>>(P);
  }
  {
    GArgs P;
    P.j[0] = mkjob(t1h, t1l, w2h, w2l, b2, nullptr, t2h, t2l,
                   B_, H_, H_, 0, H_, 3, 1, 1, 0);
    P.j[1] = aejob(5);
    P.sx = H_ / 128; P.k0 = 0; P.k1 = 0;
    gemm2job<<<dim3(H_ / 128 + 5, APAD_ / 128), 256, 0, stream>>>(P);
  }
  {
    GArgs P;
    P.j[0] = mkjob(t2h, t2l, w3h, w3l, b3, nullptr, clsh, clsl,
                   B_, H_, H_, 0, H_, 3, 0, 1, 0);
    P.j[1] = aejob(10);
    P.sx = H_ / 128; P.k0 = 0; P.k1 = 0;
    gemm2job<<<dim3(H_ / 128 + 4, APAD_ / 128), 256, 0, stream>>>(P);
  }
  {
    GArgs P;
    P.j[0] = mkjob(clsh, clsl, wihh, wihl, bih, giCls, nullptr, nullptr,
                   B_, H_, G3_, 0, G3_, 3, 0, 0, 0);
    P.j[1] = aejob(14);
    P.sx = G3_ / 128; P.k0 = 0; P.k1 = 0;
    gemm2job<<<dim3(G3_ / 128 + 4, APAD_ / 128), 256, 0, stream>>>(P);
  }

  uint32_t fk0[RL_], fk1[RL_];
  for (int j = 0; j < RL_; ++j)
    threefry2x32(0u, 42u, 0u, (uint32_t)j, &fk0[j], &fk1[j]);

  // GRU step 0 (gi = giCls, h = 0)
  gru_elem<<<(B_ * H_ + 255) / 256, 256, 0, stream>>>(giCls, bhh, hbuf, hh_, hl_);

  for (int j = 0; j < RL_; ++j) {
    // fused [logits_j (1-pass + gumbel) | gh_{j+1} (3-pass)] — both read h_j
    GArgs P;
    P.j[0] = mkjob(hh_, nullptr, whhi, nullptr, bh, vbuf, nullptr, nullptr,
                   B_, H_, A_, 0, A_, 1, 0, 0, 1);
    const int gx0 = APAD_ / 128;
    int gx = gx0;
    if (j < RL_ - 1) {
      P.j[1] = mkjob(hh_, hl_, whhh, whhl, bhh, gh, nullptr, nullptr,
                     B_, H_, G3_, 0, G3_, 3, 0, 0, 0);
      gx += G3_ / 128;
    } else {
      P.j[1] = P.j[0];
    }
    P.sx = gx0; P.k0 = fk0[j]; P.k1 = fk1[j];
    gemm2job<<<dim3(gx, B_ / 128), 256, 0, stream>>>(P);

    select_step<<<B_, 256, 0, stream>>>(vbuf, mask, idxs, giCls, AeWih, atomp,
                                        hbuf, Wh, bh, wmaxsq, gh, bhh, hh_, hl_,
                                        fk0[j], fk1[j], j);
  }

  head_k<<<B_, 256, 0, stream>>>(idxs, ae, w_mu, b_mu, w_cov, b_cov, alpha, outf);
}

// Round 9
// 1042.764 us; speedup vs baseline: 1.4470x; 1.4470x over previous
//
#include <hip/hip_runtime.h>
#include <stdint.h>
#include <math.h>

#define B_    2048
#define DIN_  512
#define H_    768
#define G3_   2304          // 3*H
#define A_    5001
#define APAD_ 5120
#define RL_   4
#define NDATA_ 56000.0f

typedef _Float16 f16x8 __attribute__((ext_vector_type(8)));
typedef _Float16 f16x4 __attribute__((ext_vector_type(4)));
typedef float    f32x4 __attribute__((ext_vector_type(4)));

// ---------------- threefry2x32 (exact JAX semantics) ----------------
__host__ __device__ __forceinline__ void threefry2x32(
    uint32_t k0, uint32_t k1, uint32_t x0, uint32_t x1,
    uint32_t* o0, uint32_t* o1)
{
  const uint32_t ks2 = k0 ^ k1 ^ 0x1BD11BDAu;
#define TF_R(r) { x0 += x1; x1 = (x1 << (r)) | (x1 >> (32 - (r))); x1 ^= x0; }
  x0 += k0; x1 += k1;
  TF_R(13) TF_R(15) TF_R(26) TF_R(6)
  x0 += k1;  x1 += ks2 + 1u;
  TF_R(17) TF_R(29) TF_R(16) TF_R(24)
  x0 += ks2; x1 += k0 + 2u;
  TF_R(13) TF_R(15) TF_R(26) TF_R(6)
  x0 += k0;  x1 += k1 + 3u;
  TF_R(17) TF_R(29) TF_R(16) TF_R(24)
  x0 += k1;  x1 += ks2 + 4u;
  TF_R(13) TF_R(15) TF_R(26) TF_R(6)
  x0 += ks2; x1 += k0 + 5u;
#undef TF_R
  *o0 = x0; *o1 = x1;
}

__device__ __forceinline__ float gumbel_for(uint32_t k0, uint32_t k1, uint32_t n)
{
  uint32_t o0, o1;
  threefry2x32(k0, k1, 0u, n, &o0, &o1);
  const uint32_t bits = o0 ^ o1;
  const float f = __uint_as_float((bits >> 9) | 0x3f800000u);  // [1,2)
  const float minv = 1e-6f;
  const float maxv = 1.0f - 1e-6f;
  const float span = maxv - minv;
  float u = __fmul_rn(f, span);
  u = __fadd_rn(u, minv);
  u = __fsub_rn(u, span);
  u = fmaxf(minv, u);
  return -logf(-logf(u));
}

// split v*64 into f16 hi/lo
struct HL { _Float16 h, l; };
__device__ __forceinline__ HL split64(float v)
{
  HL r;
  const float s = v * 64.f;
  r.h = (_Float16)s;
  r.l = (_Float16)(s - (float)r.h);
  return r;
}

// async global->LDS, 16 B/lane; LDS dst = wave-uniform base + lane*16
__device__ __forceinline__ void gload16(const void* g, void* l)
{
  __builtin_amdgcn_global_load_lds(
      (const __attribute__((address_space(1))) void*)g,
      (__attribute__((address_space(3))) void*)l, 16, 0, 0);
}

// ---------------- merged pre-split of 7 weight tensors ----------------
struct PSJobs {
  const float* src[7];
  _Float16* hi[7];
  _Float16* lo[7];
  int R[7]; int K[7];
  int cum[8];          // cumulative float4 counts
};

__global__ __launch_bounds__(256)
void presplit_all(PSJobs J)
{
  const int g = blockIdx.x * 256 + threadIdx.x;
  if (g >= J.cum[7]) return;
  int j = 0;
  while (g >= J.cum[j + 1]) ++j;
  const int i = g - J.cum[j];
  const int K = J.K[j];
  const int e = i * 4;
  const int row = e / K;
  float4 f = make_float4(0.f, 0.f, 0.f, 0.f);
  if (row < J.R[j]) f = *(const float4*)(J.src[j] + (size_t)row * K + (e - row * K));
  const HL s0 = split64(f.x), s1 = split64(f.y);
  const HL s2 = split64(f.z), s3 = split64(f.w);
  const f16x4 hv = {s0.h, s1.h, s2.h, s3.h};
  ((f16x4*)J.hi[j])[i] = hv;
  if (J.lo[j]) {
    const f16x4 lv = {s0.l, s1.l, s2.l, s3.l};
    ((f16x4*)J.lo[j])[i] = lv;
  }
}

// ---------------- combined prep: mask init + max||Wh_a||^2 + x split ------
__global__ __launch_bounds__(256)
void prep_k(const int* __restrict__ xmask, uint8_t* __restrict__ mask,
            const float* __restrict__ Wh, float* __restrict__ wmaxsq,
            const float* __restrict__ x, _Float16* __restrict__ xh,
            _Float16* __restrict__ xl)
{
  const int blk = blockIdx.x, tid = threadIdx.x;
  __shared__ float redf[256];
  __shared__ int   redi[256];
  if (blk < B_) {                       // mask init (+ step-0 row_zero fix)
    const int b = blk;
    int s = 0;
    for (int a = tid; a < A_; a += 256) {
      const int m = (xmask[(size_t)b * A_ + a] != 0) ? 1 : 0;
      mask[(size_t)b * A_ + a] = (uint8_t)m;
      s += m;
    }
    redi[tid] = s; __syncthreads();
    for (int t = 128; t > 0; t >>= 1) {
      if (tid < t) redi[tid] += redi[tid + t];
      __syncthreads();
    }
    if (tid == 0 && redi[0] == 0) mask[(size_t)b * A_] = 1;
  } else if (blk < B_ + A_) {           // max row-norm^2 of Wh
    const int a = blk - B_;
    float p = 0.f;
    for (int d = tid; d < H_; d += 256) {
      const float w = Wh[(size_t)a * H_ + d];
      p += w * w;
    }
    redf[tid] = p; __syncthreads();
    for (int t = 128; t > 0; t >>= 1) {
      if (tid < t) redf[tid] += redf[tid + t];
      __syncthreads();
    }
    if (tid == 0) atomicMax((int*)wmaxsq, __float_as_int(redf[0]));
  } else {                              // split x
    const int i = (blk - B_ - A_) * 256 + tid;
    const int n4 = B_ * DIN_ / 4;
    if (i < n4) {
      const float4 f = ((const float4*)x)[i];
      const HL s0 = split64(f.x), s1 = split64(f.y);
      const HL s2 = split64(f.z), s3 = split64(f.w);
      const f16x4 hv = {s0.h, s1.h, s2.h, s3.h};
      const f16x4 lv = {s0.l, s1.l, s2.l, s3.l};
      ((f16x4*)xh)[i] = hv;
      ((f16x4*)xl)[i] = lv;
    }
  }
}

// ================= generic 2-job f16-split MFMA GEMM =================
// Job: C[m, n0+n] = A[m,:] @ B[n0+n,:] + bias.  npass=3: hihi+lohi+hilo.
// np3: BK=32 (planes = hi/lo).  np1: BK=64 (planes = two 32-K subtiles,
// round = barrier / frags0 / MFMA0 / frags1 / barrier / DMA-next / MFMA1).
struct GJob {
  const _Float16 *Ah, *Al, *Bh, *Bl;
  const float* bias;
  float* C;
  _Float16 *Ch, *Cl;
  int M, K, ldc, n0, Nv;   // store iff n_global < Nv; offset m*ldc + n_global
  int npass, act, wsplit, gum;
};
struct GArgs { GJob j[2]; int sx; uint32_t k0, k1; };

__global__ __launch_bounds__(256)
void gemm2job(GArgs P)
{
  __shared__ _Float16 sA[2][128 * 32];
  __shared__ _Float16 sB[2][128 * 32];

  const int jid = (blockIdx.x < P.sx) ? 0 : 1;
  const GJob J = P.j[jid];
  const int bxx = blockIdx.x - (jid ? P.sx : 0);
  const int bm = blockIdx.y * 128;
  if (bm >= J.M) return;
  const int bn = J.n0 + bxx * 128;

  const int tid = threadIdx.x;
  const int lane = tid & 63, wave = tid >> 6;
  const int wx = wave & 1, wy = wave >> 1;
  const int q = lane >> 4, mr = lane & 15;
  const int K = J.K;
  const int np3 = (J.npass == 3);

  f32x4 acc[4][4];
#pragma unroll
  for (int i = 0; i < 4; ++i)
#pragma unroll
    for (int j = 0; j < 4; ++j) acc[i][j] = (f32x4)0.f;

  const int abase = (wy * 64 + mr) * 32 + q * 8;
  const int bbase = (wx * 64 + mr) * 32 + q * 8;

  if (np3) {
    // ---- 3-pass, BK=32: plane0 = hi, plane1 = lo ----
    auto stage = [&](int k0) {
#pragma unroll
      for (int t = 0; t < 2; ++t) {
        const int c = wave * 2 + t;               // chunk: 16 rows x 32 f16
        const int row = c * 16 + (lane >> 2);
        const int kc = (lane & 3) * 8;
        const size_t ga = (size_t)(bm + row) * K + k0 + kc;
        const size_t gb = (size_t)(bn + row) * K + k0 + kc;
        gload16(J.Ah + ga, &sA[0][c * 512]);
        gload16(J.Bh + gb, &sB[0][c * 512]);
        gload16(J.Al + ga, &sA[1][c * 512]);
        gload16(J.Bl + gb, &sB[1][c * 512]);
      }
    };
    stage(0);
    const int T = K / 32;
    for (int t = 0; t < T; ++t) {
      __syncthreads();                  // DMA(t) complete
      f16x8 ah[4], al[4], bhv[4], blv[4];
#pragma unroll
      for (int mi = 0; mi < 4; ++mi) {
        ah[mi]  = *(const f16x8*)&sA[0][abase + mi * 512];
        bhv[mi] = *(const f16x8*)&sB[0][bbase + mi * 512];
        al[mi]  = *(const f16x8*)&sA[1][abase + mi * 512];
        blv[mi] = *(const f16x8*)&sB[1][bbase + mi * 512];
      }
      __syncthreads();                  // reads done -> buffers free
      if (t + 1 < T) stage((t + 1) * 32);
#pragma unroll
      for (int ni = 0; ni < 4; ++ni)
#pragma unroll
        for (int mi = 0; mi < 4; ++mi) {
          acc[mi][ni] = __builtin_amdgcn_mfma_f32_16x16x32_f16(ah[mi], bhv[ni], acc[mi][ni], 0, 0, 0);
          acc[mi][ni] = __builtin_amdgcn_mfma_f32_16x16x32_f16(al[mi], bhv[ni], acc[mi][ni], 0, 0, 0);
          acc[mi][ni] = __builtin_amdgcn_mfma_f32_16x16x32_f16(ah[mi], blv[ni], acc[mi][ni], 0, 0, 0);
        }
    }
  } else {
    // ---- 1-pass, BK=64: plane0 = k..k+31, plane1 = k+32..k+63 ----
    auto stage64 = [&](int k0) {
#pragma unroll
      for (int t = 0; t < 2; ++t) {
        const int c = wave * 2 + t;
        const int row = c * 16 + (lane >> 2);
        const int kc = (lane & 3) * 8;
        const size_t ga = (size_t)(bm + row) * K + k0 + kc;
        const size_t gb = (size_t)(bn + row) * K + k0 + kc;
        gload16(J.Ah + ga, &sA[0][c * 512]);
        gload16(J.Bh + gb, &sB[0][c * 512]);
        gload16(J.Ah + ga + 32, &sA[1][c * 512]);
        gload16(J.Bh + gb + 32, &sB[1][c * 512]);
      }
    };
    stage64(0);
    const int T2 = K / 64;
    for (int t = 0; t < T2; ++t) {
      __syncthreads();                  // DMA(t) complete
      f16x8 a0[4], b0[4];
#pragma unroll
      for (int mi = 0; mi < 4; ++mi) {
        a0[mi] = *(const f16x8*)&sA[0][abase + mi * 512];
        b0[mi] = *(const f16x8*)&sB[0][bbase + mi * 512];
      }
#pragma unroll
      for (int ni = 0; ni < 4; ++ni)
#pragma unroll
        for (int mi = 0; mi < 4; ++mi)
          acc[mi][ni] = __builtin_amdgcn_mfma_f32_16x16x32_f16(a0[mi], b0[ni], acc[mi][ni], 0, 0, 0);
      f16x8 a1[4], b1[4];
#pragma unroll
      for (int mi = 0; mi < 4; ++mi) {
        a1[mi] = *(const f16x8*)&sA[1][abase + mi * 512];
        b1[mi] = *(const f16x8*)&sB[1][bbase + mi * 512];
      }
      __syncthreads();                  // all reads done -> planes free
      if (t + 1 < T2) stage64((t + 1) * 64);  // flies during MFMA1
#pragma unroll
      for (int ni = 0; ni < 4; ++ni)
#pragma unroll
        for (int mi = 0; mi < 4; ++mi)
          acc[mi][ni] = __builtin_amdgcn_mfma_f32_16x16x32_f16(a1[mi], b1[ni], acc[mi][ni], 0, 0, 0);
    }
  }

  // epilogue: C/D layout col=lane&15, row=(lane>>4)*4+reg
  const float sc = 1.f / 4096.f;
#pragma unroll
  for (int ni = 0; ni < 4; ++ni) {
    const int n = bn + wx * 64 + ni * 16 + mr;
    if (n >= J.Nv) continue;
    const float bv = J.bias ? J.bias[n] : 0.f;
#pragma unroll
    for (int mi = 0; mi < 4; ++mi) {
      const int m0 = bm + wy * 64 + mi * 16 + q * 4;
#pragma unroll
      for (int r = 0; r < 4; ++r) {
        const int m = m0 + r;
        float v = acc[mi][ni][r] * sc + bv;
        if (J.act) v = fmaxf(v, 0.f);
        if (J.gum) v += gumbel_for(P.k0, P.k1, (uint32_t)(m * J.ldc + n));
        const size_t off = (size_t)m * J.ldc + n;
        if (J.C) J.C[off] = v;
        if (J.wsplit) {
          const HL s = split64(v);
          J.Ch[off] = s.h;
          J.Cl[off] = s.l;
        }
      }
    }
  }
}

// ---------------- GRU elementwise (step 0 only) + fused h split ----------
__global__ __launch_bounds__(256)
void gru_elem(const float* __restrict__ gi, const float* __restrict__ bhh,
              float* __restrict__ h, _Float16* __restrict__ hh_,
              _Float16* __restrict__ hl_)
{
  const int i = blockIdx.x * 256 + threadIdx.x;
  if (i >= B_ * H_) return;
  const int b = i / H_;
  const int d = i - b * H_;
  const float* gib = gi + (size_t)b * G3_;
  const float ir = gib[d], iz = gib[H_ + d], in_ = gib[2 * H_ + d];
  const float hr = bhh[d], hz = bhh[H_ + d], hn = bhh[2 * H_ + d];
  const float r = 1.f / (1.f + expf(-(ir + hr)));
  const float z = 1.f / (1.f + expf(-(iz + hz)));
  const float n = tanhf(in_ + r * hn);
  const float hv = (1.f - z) * n;      // h_prev = 0
  h[i] = hv;
  const HL s = split64(hv);
  hh_[i] = s.h; hl_[i] = s.l;
}

// ---------------- select + fused GRU for the next step --------------------
__global__ __launch_bounds__(256)
void select_step(const float* __restrict__ v, uint8_t* __restrict__ mask,
                 int* __restrict__ idxs, const float* __restrict__ giCls,
                 const float* __restrict__ AeWih, float* __restrict__ atomp,
                 float* __restrict__ hbuf, const float* __restrict__ WhF,
                 const float* __restrict__ bh, const float* __restrict__ wmaxsq,
                 const float* __restrict__ gh, const float* __restrict__ bhh,
                 _Float16* __restrict__ hh_, _Float16* __restrict__ hl_,
                 uint32_t k0, uint32_t k1, int step)
{
  const int b = blockIdx.x, tid = threadIdx.x;
  uint8_t* mrow = mask + (size_t)b * A_;
  __shared__ float vsh[A_];        // masked v row cache (20 KB)
  __shared__ float hsh[H_];
  __shared__ float gish[G3_];
  __shared__ float sv[256];
  __shared__ int   si[256];
  __shared__ int   s_list[64];
  __shared__ int   s_n;
  __shared__ int   s_sel;

  // h_j row -> LDS + ||h||^2
  float hp = 0.f;
  for (int d = tid; d < H_; d += 256) {
    const float t = hbuf[(size_t)b * H_ + d];
    hsh[d] = t; hp += t * t;
  }
  sv[tid] = hp; __syncthreads();
  for (int t = 128; t > 0; t >>= 1) {
    if (tid < t) sv[tid] += sv[tid + t];
    __syncthreads();
  }
  const float hn2 = sv[0];
  __syncthreads();

  // mask update
  if (step > 0) {
    const int prev = idxs[(step - 1) * B_ + b];
    if (prev == 0)
      for (int a = tid; a < A_; a += 256) mrow[a] = 0;
    __syncthreads();
    if (tid == 0) mrow[0] = 1;
  }
  if (tid == 0) s_n = 0;
  __syncthreads();

  // single pass: mask-apply, cache in LDS, track max
  const float* vrow = v + (size_t)b * A_;
  float bv = -INFINITY; int bi = A_;
  for (int a = tid; a < A_; a += 256) {
    const float val = mrow[a] ? vrow[a] : -INFINITY;
    vsh[a] = val;
    if (val > bv) { bv = val; bi = a; }
  }
  sv[tid] = bv; si[tid] = bi; __syncthreads();
  for (int t = 128; t > 0; t >>= 1) {
    if (tid < t) {
      const float v2 = sv[tid + t]; const int i2 = si[tid + t];
      if (v2 > sv[tid] || (v2 == sv[tid] && i2 < si[tid])) { sv[tid] = v2; si[tid] = i2; }
    }
    __syncthreads();
  }
  const float amax = sv[0];
  __syncthreads();

  // |approx-exact| <= 2^-10 * ||h|| * max||w_a||  (x2 safety)
  const float delta = 2.0f * 0.0009765625f * sqrtf(hn2 * wmaxsq[0]);
  const float thr = amax - 2.f * delta;

  for (int a = tid; a < A_; a += 256)
    if (vsh[a] >= thr) {
      const int p = atomicAdd(&s_n, 1);
      if (p < 64) s_list[p] = a;
    }
  __syncthreads();
  const int nc = (s_n < 64) ? s_n : 64;

  // exact fp32 re-eval; argmax with lowest-index tie-break
  const uint32_t nbase = (uint32_t)b * (uint32_t)A_;
  float best = -INFINITY; int bestA = A_;
  for (int c = 0; c < nc; ++c) {
    const int a = s_list[c];
    const float* wr = WhF + (size_t)a * H_;
    float p = 0.f;
    for (int d = tid; d < H_; d += 256) p += hsh[d] * wr[d];
    sv[tid] = p; __syncthreads();
    for (int t = 128; t > 0; t >>= 1) {
      if (tid < t) sv[tid] += sv[tid + t];
      __syncthreads();
    }
    if (tid == 0) {
      const float ev = sv[0] + bh[a] + gumbel_for(k0, k1, nbase + (uint32_t)a);
      if (ev > best || (ev == best && a < bestA)) { best = ev; bestA = a; }
    }
    __syncthreads();
  }
  if (tid == 0) {
    s_sel = bestA;
    mrow[bestA] = 0;
    idxs[step * B_ + b] = bestA;
    atomp[(size_t)b * (RL_ * A_) + (size_t)step * A_ + bestA] = 1.0f;
  }
  __syncthreads();

  if (step < RL_ - 1) {
    // gi_{j+1} row = giCls + AeWih[sel]  (LDS), then fused GRU -> h_{j+1}
    const int sel = s_sel;
    const float* ar = AeWih + (size_t)sel * G3_;
    const float* gr = giCls + (size_t)b * G3_;
    for (int d = tid; d < G3_; d += 256) gish[d] = gr[d] + ar[d];
    __syncthreads();
    const float* ghb = gh + (size_t)b * G3_;
    for (int d = tid; d < H_; d += 256) {
      const float r = 1.f / (1.f + expf(-(gish[d] + ghb[d])));
      const float z = 1.f / (1.f + expf(-(gish[H_ + d] + ghb[H_ + d])));
      const float n = tanhf(gish[2 * H_ + d] + r * ghb[2 * H_ + d]);
      const float hv = (1.f - z) * n + z * hsh[d];
      hbuf[(size_t)b * H_ + d] = hv;
      const HL s = split64(hv);
      hh_[(size_t)b * H_ + d] = s.h;
      hl_[(size_t)b * H_ + d] = s.l;
    }
  }
}

// ---------------- final heads ----------------
__global__ __launch_bounds__(256)
void head_k(const int* __restrict__ idxs, const float* __restrict__ ae,
            const float* __restrict__ w_mu, const float* __restrict__ b_mu,
            const float* __restrict__ w_cov, const float* __restrict__ b_cov,
            const float* __restrict__ alpha, float* __restrict__ outf)
{
  const int b = blockIdx.x, tid = threadIdx.x;
  const int i0 = idxs[0 * B_ + b], i1 = idxs[1 * B_ + b];
  const int i2 = idxs[2 * B_ + b], i3 = idxs[3 * B_ + b];
  const float* r0 = ae + (size_t)i0 * H_;
  const float* r1 = ae + (size_t)i1 * H_;
  const float* r2 = ae + (size_t)i2 * H_;
  const float* r3 = ae + (size_t)i3 * H_;
  float pmu = 0.f, pcv = 0.f;
  for (int d = tid; d < H_; d += 256) {
    const float a = r0[d] + r1[d] + r2[d] + r3[d];
    pmu += a * w_mu[d];
    pcv += a * w_cov[d];
  }
  __shared__ float smu[256], scv[256];
  smu[tid] = pmu; scv[tid] = pcv;
  __syncthreads();
  for (int s = 128; s > 0; s >>= 1) {
    if (tid < s) { smu[tid] += smu[tid + s]; scv[tid] += scv[tid + s]; }
    __syncthreads();
  }
  if (tid == 0) {
    const float mu = 1.f / (1.f + expf(-(smu[0] + b_mu[0])));
    const float cv = 1.f / (1.f + expf(-(scv[0] + b_cov[0])));
    const float n = cv * NDATA_;
    const float inv = alpha[0] / n;
    const float pp = (mu + inv) / (1.f + 2.f * inv);
    outf[2 * b + 0] = logf(1.f - pp);
    outf[2 * b + 1] = logf(pp);
    float* cp = outf + 2 * B_ + (size_t)B_ * RL_ * A_;
    cp[2 * b + 0] = 1.f - pp;
    cp[2 * b + 1] = pp;
  }
}

// ---------------- launch ----------------
extern "C" void kernel_launch(void* const* d_in, const int* in_sizes, int n_in,
                              void* d_out, int out_size, void* d_ws, size_t ws_size,
                              hipStream_t stream)
{
  const float* x     = (const float*)d_in[0];
  const int*   xmask = (const int*)d_in[1];
  const float* W1 = (const float*)d_in[2];  const float* b1 = (const float*)d_in[3];
  const float* W2 = (const float*)d_in[4];  const float* b2 = (const float*)d_in[5];
  const float* W3 = (const float*)d_in[6];  const float* b3 = (const float*)d_in[7];
  const float* Wih = (const float*)d_in[8]; const float* bih = (const float*)d_in[9];
  const float* Whh = (const float*)d_in[10];const float* bhh = (const float*)d_in[11];
  const float* Wh = (const float*)d_in[12]; const float* bh = (const float*)d_in[13];
  const float* ae = (const float*)d_in[14];
  const float* w_mu = (const float*)d_in[15];  const float* b_mu = (const float*)d_in[16];
  const float* w_cov = (const float*)d_in[17]; const float* b_cov = (const float*)d_in[18];
  const float* alpha = (const float*)d_in[19];

  char* ws = (char*)d_ws;
  size_t off = 0;
  auto alloc = [&](size_t bytes) -> void* {
    void* p = ws + off;
    off += (bytes + 255) & ~(size_t)255;
    return p;
  };
  float* hbuf   = (float*)alloc((size_t)B_ * H_ * 4);
  float* giCls  = (float*)alloc((size_t)B_ * G3_ * 4);
  float* gh     = (float*)alloc((size_t)B_ * G3_ * 4);
  float* vbuf   = (float*)alloc((size_t)B_ * A_ * 4);
  float* AeWih  = (float*)alloc((size_t)APAD_ * G3_ * 4);
  uint8_t* mask = (uint8_t*)alloc((size_t)B_ * A_);
  int* idxs     = (int*)alloc((size_t)RL_ * B_ * 4);
  _Float16* hh_ = (_Float16*)alloc((size_t)B_ * H_ * 2);
  _Float16* hl_ = (_Float16*)alloc((size_t)B_ * H_ * 2);
  _Float16* clsh = (_Float16*)alloc((size_t)B_ * H_ * 2);
  _Float16* clsl = (_Float16*)alloc((size_t)B_ * H_ * 2);
  _Float16* xh  = (_Float16*)alloc((size_t)B_ * DIN_ * 2);
  _Float16* xl  = (_Float16*)alloc((size_t)B_ * DIN_ * 2);
  _Float16* t1h = (_Float16*)alloc((size_t)B_ * H_ * 2);
  _Float16* t1l = (_Float16*)alloc((size_t)B_ * H_ * 2);
  _Float16* t2h = (_Float16*)alloc((size_t)B_ * H_ * 2);
  _Float16* t2l = (_Float16*)alloc((size_t)B_ * H_ * 2);
  _Float16* w1h = (_Float16*)alloc((size_t)H_ * DIN_ * 2);
  _Float16* w1l = (_Float16*)alloc((size_t)H_ * DIN_ * 2);
  _Float16* w2h = (_Float16*)alloc((size_t)H_ * H_ * 2);
  _Float16* w2l = (_Float16*)alloc((size_t)H_ * H_ * 2);
  _Float16* w3h = (_Float16*)alloc((size_t)H_ * H_ * 2);
  _Float16* w3l = (_Float16*)alloc((size_t)H_ * H_ * 2);
  _Float16* wihh = (_Float16*)alloc((size_t)G3_ * H_ * 2);
  _Float16* wihl = (_Float16*)alloc((size_t)G3_ * H_ * 2);
  _Float16* whhh = (_Float16*)alloc((size_t)G3_ * H_ * 2);
  _Float16* whhl = (_Float16*)alloc((size_t)G3_ * H_ * 2);
  _Float16* whhi = (_Float16*)alloc((size_t)APAD_ * H_ * 2);  // Wh hi (1-pass)
  _Float16* aeh  = (_Float16*)alloc((size_t)APAD_ * H_ * 2);
  _Float16* ael  = (_Float16*)alloc((size_t)APAD_ * H_ * 2);
  float* wmaxsq = (float*)alloc(4);

  float* outf  = (float*)d_out;
  float* atomp = outf + 2 * B_;

  (void)hipMemsetAsync(d_out, 0, (size_t)out_size * sizeof(float), stream);
  (void)hipMemsetAsync(wmaxsq, 0, 4, stream);

  // merged presplit: W1 W2 W3 Wih Whh Wh(hi) ae(hi+lo)
  PSJobs J;
  const float* srcs[7] = {W1, W2, W3, Wih, Whh, Wh, ae};
  _Float16* his[7] = {w1h, w2h, w3h, wihh, whhh, whhi, aeh};
  _Float16* los[7] = {w1l, w2l, w3l, wihl, whhl, nullptr, ael};
  const int Rs[7]    = {H_, H_, H_, G3_, G3_, A_, A_};
  const int Rpads[7] = {H_, H_, H_, G3_, G3_, APAD_, APAD_};
  const int Ks[7]    = {DIN_, H_, H_, H_, H_, H_, H_};
  J.cum[0] = 0;
  for (int j = 0; j < 7; ++j) {
    J.src[j] = srcs[j]; J.hi[j] = his[j]; J.lo[j] = los[j];
    J.R[j] = Rs[j]; J.K[j] = Ks[j];
    J.cum[j + 1] = J.cum[j] + Rpads[j] * Ks[j] / 4;
  }
  presplit_all<<<(J.cum[7] + 255) / 256, 256, 0, stream>>>(J);

  prep_k<<<B_ + A_ + (B_ * DIN_ / 4 + 255) / 256, 256, 0, stream>>>(
      xmask, mask, Wh, wmaxsq, x, xh, xl);

  auto mkjob = [](const _Float16* Ah, const _Float16* Al, const _Float16* Bh,
                  const _Float16* Bl, const float* bias, float* C,
                  _Float16* Ch, _Float16* Cl, int M, int K, int ldc,
                  int n0, int Nv, int npass, int act, int wsplit, int gum) {
    GJob g; g.Ah = Ah; g.Al = Al; g.Bh = Bh; g.Bl = Bl; g.bias = bias;
    g.C = C; g.Ch = Ch; g.Cl = Cl; g.M = M; g.K = K; g.ldc = ldc;
    g.n0 = n0; g.Nv = Nv; g.npass = npass; g.act = act; g.wsplit = wsplit;
    g.gum = gum;
    return g;
  };
  auto aejob = [&](int t0) {   // AeWih column-chunk job
    return mkjob(aeh, ael, wihh, wihl, nullptr, AeWih, nullptr, nullptr,
                 APAD_, H_, G3_, t0 * 128, G3_, 3, 0, 0, 0);
  };

  // MLP chain with AeWih column chunks (5,5,4,4 tiles) as concurrent filler
  {
    GArgs P;
    P.j[0] = mkjob(xh, xl, w1h, w1l, b1, nullptr, t1h, t1l,
                   B_, DIN_, H_, 0, H_, 3, 1, 1, 0);
    P.j[1] = aejob(0);
    P.sx = H_ / 128; P.k0 = 0; P.k1 = 0;
    gemm2job<<<dim3(H_ / 128 + 5, APAD_ / 128), 256, 0, stream>>>(P);
  }
  {
    GArgs P;
    P.j[0] = mkjob(t1h, t1l, w2h, w2l, b2, nullptr, t2h, t2l,
                   B_, H_, H_, 0, H_, 3, 1, 1, 0);
    P.j[1] = aejob(5);
    P.sx = H_ / 128; P.k0 = 0; P.k1 = 0;
    gemm2job<<<dim3(H_ / 128 + 5, APAD_ / 128), 256, 0, stream>>>(P);
  }
  {
    GArgs P;
    P.j[0] = mkjob(t2h, t2l, w3h, w3l, b3, nullptr, clsh, clsl,
                   B_, H_, H_, 0, H_, 3, 0, 1, 0);
    P.j[1] = aejob(10);
    P.sx = H_ / 128; P.k0 = 0; P.k1 = 0;
    gemm2job<<<dim3(H_ / 128 + 4, APAD_ / 128), 256, 0, stream>>>(P);
  }
  {
    GArgs P;
    P.j[0] = mkjob(clsh, clsl, wihh, wihl, bih, giCls, nullptr, nullptr,
                   B_, H_, G3_, 0, G3_, 3, 0, 0, 0);
    P.j[1] = aejob(14);
    P.sx = G3_ / 128; P.k0 = 0; P.k1 = 0;
    gemm2job<<<dim3(G3_ / 128 + 4, APAD_ / 128), 256, 0, stream>>>(P);
  }

  uint32_t fk0[RL_], fk1[RL_];
  for (int j = 0; j < RL_; ++j)
    threefry2x32(0u, 42u, 0u, (uint32_t)j, &fk0[j], &fk1[j]);

  // GRU step 0 (gi = giCls, h = 0)
  gru_elem<<<(B_ * H_ + 255) / 256, 256, 0, stream>>>(giCls, bhh, hbuf, hh_, hl_);

  for (int j = 0; j < RL_; ++j) {
    // fused [logits_j (1-pass BK64 + gumbel) | gh_{j+1} (3-pass)] — share h_j
    GArgs P;
    P.j[0] = mkjob(hh_, nullptr, whhi, nullptr, bh, vbuf, nullptr, nullptr,
                   B_, H_, A_, 0, A_, 1, 0, 0, 1);
    const int gx0 = APAD_ / 128;
    int gx = gx0;
    if (j < RL_ - 1) {
      P.j[1] = mkjob(hh_, hl_, whhh, whhl, bhh, gh, nullptr, nullptr,
                     B_, H_, G3_, 0, G3_, 3, 0, 0, 0);
      gx += G3_ / 128;
    } else {
      P.j[1] = P.j[0];
    }
    P.sx = gx0; P.k0 = fk0[j]; P.k1 = fk1[j];
    gemm2job<<<dim3(gx, B_ / 128), 256, 0, stream>>>(P);

    select_step<<<B_, 256, 0, stream>>>(vbuf, mask, idxs, giCls, AeWih, atomp,
                                        hbuf, Wh, bh, wmaxsq, gh, bhh, hh_, hl_,
                                        fk0[j], fk1[j], j);
  }

  head_k<<<B_, 256, 0, stream>>>(idxs, ae, w_mu, b_mu, w_cov, b_cov, alpha, outf);
}

// Round 10
// 981.271 us; speedup vs baseline: 1.5377x; 1.0627x over previous
//
#include <hip/hip_runtime.h>
#include <stdint.h>
#include <math.h>

#define B_    2048
#define DIN_  512
#define H_    768
#define G3_   2304          // 3*H
#define A_    5001
#define APAD_ 5120
#define RL_   4
#define NDATA_ 56000.0f

typedef _Float16 f16x8 __attribute__((ext_vector_type(8)));
typedef _Float16 f16x4 __attribute__((ext_vector_type(4)));
typedef float    f32x4 __attribute__((ext_vector_type(4)));

// ---------------- threefry2x32 (exact JAX semantics) ----------------
__host__ __device__ __forceinline__ void threefry2x32(
    uint32_t k0, uint32_t k1, uint32_t x0, uint32_t x1,
    uint32_t* o0, uint32_t* o1)
{
  const uint32_t ks2 = k0 ^ k1 ^ 0x1BD11BDAu;
#define TF_R(r) { x0 += x1; x1 = (x1 << (r)) | (x1 >> (32 - (r))); x1 ^= x0; }
  x0 += k0; x1 += k1;
  TF_R(13) TF_R(15) TF_R(26) TF_R(6)
  x0 += k1;  x1 += ks2 + 1u;
  TF_R(17) TF_R(29) TF_R(16) TF_R(24)
  x0 += ks2; x1 += k0 + 2u;
  TF_R(13) TF_R(15) TF_R(26) TF_R(6)
  x0 += k0;  x1 += k1 + 3u;
  TF_R(17) TF_R(29) TF_R(16) TF_R(24)
  x0 += k1;  x1 += ks2 + 4u;
  TF_R(13) TF_R(15) TF_R(26) TF_R(6)
  x0 += ks2; x1 += k0 + 5u;
#undef TF_R
  *o0 = x0; *o1 = x1;
}

__device__ __forceinline__ float gumbel_for(uint32_t k0, uint32_t k1, uint32_t n)
{
  uint32_t o0, o1;
  threefry2x32(k0, k1, 0u, n, &o0, &o1);
  const uint32_t bits = o0 ^ o1;
  const float f = __uint_as_float((bits >> 9) | 0x3f800000u);  // [1,2)
  const float minv = 1e-6f;
  const float maxv = 1.0f - 1e-6f;
  const float span = maxv - minv;
  float u = __fmul_rn(f, span);
  u = __fadd_rn(u, minv);
  u = __fsub_rn(u, span);
  u = fmaxf(minv, u);
  return -logf(-logf(u));
}

// split v*64 into f16 hi/lo
struct HL { _Float16 h, l; };
__device__ __forceinline__ HL split64(float v)
{
  HL r;
  const float s = v * 64.f;
  r.h = (_Float16)s;
  r.l = (_Float16)(s - (float)r.h);
  return r;
}

// async global->LDS, 16 B/lane; LDS dst = wave-uniform base + lane*16
__device__ __forceinline__ void gload16(const void* g, void* l)
{
  __builtin_amdgcn_global_load_lds(
      (const __attribute__((address_space(1))) void*)g,
      (__attribute__((address_space(3))) void*)l, 16, 0, 0);
}

// ---------------- merged pre-split of 7 weight tensors (opt transpose) -----
struct PSJobs {
  const float* src[7];
  _Float16* hi[7];
  _Float16* lo[7];
  int R[7]; int K[7]; int trans[7];   // trans: out[r][k] = src[k*R + r]
  int cum[8];          // cumulative float4 counts
};

__global__ __launch_bounds__(256)
void presplit_all(PSJobs J)
{
  const int g = blockIdx.x * 256 + threadIdx.x;
  if (g >= J.cum[7]) return;
  int j = 0;
  while (g >= J.cum[j + 1]) ++j;
  const int i = g - J.cum[j];
  const int K = J.K[j];
  const int e = i * 4;
  const int row = e / K;
  const int col = e - row * K;
  float4 f = make_float4(0.f, 0.f, 0.f, 0.f);
  if (J.trans[j]) {
    // source is [K][R]; out[row][col+t] = src[(col+t)*R + row]
    const int R = J.R[j];
    f.x = J.src[j][(size_t)(col + 0) * R + row];
    f.y = J.src[j][(size_t)(col + 1) * R + row];
    f.z = J.src[j][(size_t)(col + 2) * R + row];
    f.w = J.src[j][(size_t)(col + 3) * R + row];
  } else if (row < J.R[j]) {
    f = *(const float4*)(J.src[j] + (size_t)row * K + col);
  }
  const HL s0 = split64(f.x), s1 = split64(f.y);
  const HL s2 = split64(f.z), s3 = split64(f.w);
  const f16x4 hv = {s0.h, s1.h, s2.h, s3.h};
  ((f16x4*)J.hi[j])[i] = hv;
  if (J.lo[j]) {
    const f16x4 lv = {s0.l, s1.l, s2.l, s3.l};
    ((f16x4*)J.lo[j])[i] = lv;
  }
}

// ------- prep: mask init + max||Wh_a||^2 + x split + b' = Wih@b3 + bih -----
__global__ __launch_bounds__(256)
void prep_k(const int* __restrict__ xmask, uint8_t* __restrict__ mask,
            const float* __restrict__ Wh, float* __restrict__ wmaxsq,
            const float* __restrict__ x, _Float16* __restrict__ xh,
            _Float16* __restrict__ xl, const float* __restrict__ Wih,
            const float* __restrict__ b3, const float* __restrict__ bih,
            float* __restrict__ bprime)
{
  const int blk = blockIdx.x, tid = threadIdx.x;
  const int XB = (B_ * DIN_ / 4 + 255) / 256;
  __shared__ float redf[256];
  __shared__ int   redi[256];
  if (blk < B_) {                       // mask init (+ step-0 row_zero fix)
    const int b = blk;
    int s = 0;
    for (int a = tid; a < A_; a += 256) {
      const int m = (xmask[(size_t)b * A_ + a] != 0) ? 1 : 0;
      mask[(size_t)b * A_ + a] = (uint8_t)m;
      s += m;
    }
    redi[tid] = s; __syncthreads();
    for (int t = 128; t > 0; t >>= 1) {
      if (tid < t) redi[tid] += redi[tid + t];
      __syncthreads();
    }
    if (tid == 0 && redi[0] == 0) mask[(size_t)b * A_] = 1;
  } else if (blk < B_ + A_) {           // max row-norm^2 of Wh
    const int a = blk - B_;
    float p = 0.f;
    for (int d = tid; d < H_; d += 256) {
      const float w = Wh[(size_t)a * H_ + d];
      p += w * w;
    }
    redf[tid] = p; __syncthreads();
    for (int t = 128; t > 0; t >>= 1) {
      if (tid < t) redf[tid] += redf[tid + t];
      __syncthreads();
    }
    if (tid == 0) atomicMax((int*)wmaxsq, __float_as_int(redf[0]));
  } else if (blk < B_ + A_ + XB) {      // split x
    const int i = (blk - B_ - A_) * 256 + tid;
    const int n4 = B_ * DIN_ / 4;
    if (i < n4) {
      const float4 f = ((const float4*)x)[i];
      const HL s0 = split64(f.x), s1 = split64(f.y);
      const HL s2 = split64(f.z), s3 = split64(f.w);
      const f16x4 hv = {s0.h, s1.h, s2.h, s3.h};
      const f16x4 lv = {s0.l, s1.l, s2.l, s3.l};
      ((f16x4*)xh)[i] = hv;
      ((f16x4*)xl)[i] = lv;
    }
  } else {                              // b'[n] = Wih[n,:]@b3 + bih[n]
    const int n = blk - B_ - A_ - XB;
    float p = 0.f;
    for (int d = tid; d < H_; d += 256)
      p += Wih[(size_t)n * H_ + d] * b3[d];
    redf[tid] = p; __syncthreads();
    for (int t = 128; t > 0; t >>= 1) {
      if (tid < t) redf[tid] += redf[tid + t];
      __syncthreads();
    }
    if (tid == 0) bprime[n] = redf[0] + bih[n];
  }
}

// ================= generic 3-job f16-split MFMA GEMM =================
// Job: C[m, n0+n] = A[m,:] @ B[n0+n,:] + bias.  npass=3: hihi+lohi+hilo.
// np3: BK=32 (planes = hi/lo).  np1: BK=64 (planes = two 32-K subtiles).
struct GJob {
  const _Float16 *Ah, *Al, *Bh, *Bl;
  const float* bias;
  float* C;
  _Float16 *Ch, *Cl;
  int M, K, ldc, n0, Nv;   // store iff n_global < Nv; offset m*ldc + n_global
  int npass, act, wsplit, gum;
};
struct GArgs { GJob j[3]; int sx1, sx2; uint32_t k0, k1; };

__global__ __launch_bounds__(256)
void gemm2job(GArgs P)
{
  __shared__ _Float16 sA[2][128 * 32];
  __shared__ _Float16 sB[2][128 * 32];

  const int bx = blockIdx.x;
  const int jid = (bx < P.sx1) ? 0 : ((bx < P.sx2) ? 1 : 2);
  const GJob J = P.j[jid];
  const int bxx = bx - ((jid == 0) ? 0 : ((jid == 1) ? P.sx1 : P.sx2));
  const int bm = blockIdx.y * 128;
  if (bm >= J.M) return;
  const int bn = J.n0 + bxx * 128;

  const int tid = threadIdx.x;
  const int lane = tid & 63, wave = tid >> 6;
  const int wx = wave & 1, wy = wave >> 1;
  const int q = lane >> 4, mr = lane & 15;
  const int K = J.K;
  const int np3 = (J.npass == 3);

  f32x4 acc[4][4];
#pragma unroll
  for (int i = 0; i < 4; ++i)
#pragma unroll
    for (int j = 0; j < 4; ++j) acc[i][j] = (f32x4)0.f;

  const int abase = (wy * 64 + mr) * 32 + q * 8;
  const int bbase = (wx * 64 + mr) * 32 + q * 8;

  if (np3) {
    // ---- 3-pass, BK=32: plane0 = hi, plane1 = lo ----
    auto stage = [&](int k0) {
#pragma unroll
      for (int t = 0; t < 2; ++t) {
        const int c = wave * 2 + t;               // chunk: 16 rows x 32 f16
        const int row = c * 16 + (lane >> 2);
        const int kc = (lane & 3) * 8;
        const size_t ga = (size_t)(bm + row) * K + k0 + kc;
        const size_t gb = (size_t)(bn + row) * K + k0 + kc;
        gload16(J.Ah + ga, &sA[0][c * 512]);
        gload16(J.Bh + gb, &sB[0][c * 512]);
        gload16(J.Al + ga, &sA[1][c * 512]);
        gload16(J.Bl + gb, &sB[1][c * 512]);
      }
    };
    stage(0);
    const int T = K / 32;
    for (int t = 0; t < T; ++t) {
      __syncthreads();                  // DMA(t) complete
      f16x8 ah[4], al[4], bhv[4], blv[4];
#pragma unroll
      for (int mi = 0; mi < 4; ++mi) {
        ah[mi]  = *(const f16x8*)&sA[0][abase + mi * 512];
        bhv[mi] = *(const f16x8*)&sB[0][bbase + mi * 512];
        al[mi]  = *(const f16x8*)&sA[1][abase + mi * 512];
        blv[mi] = *(const f16x8*)&sB[1][bbase + mi * 512];
      }
      __syncthreads();                  // reads done -> buffers free
      if (t + 1 < T) stage((t + 1) * 32);
#pragma unroll
      for (int ni = 0; ni < 4; ++ni)
#pragma unroll
        for (int mi = 0; mi < 4; ++mi) {
          acc[mi][ni] = __builtin_amdgcn_mfma_f32_16x16x32_f16(ah[mi], bhv[ni], acc[mi][ni], 0, 0, 0);
          acc[mi][ni] = __builtin_amdgcn_mfma_f32_16x16x32_f16(al[mi], bhv[ni], acc[mi][ni], 0, 0, 0);
          acc[mi][ni] = __builtin_amdgcn_mfma_f32_16x16x32_f16(ah[mi], blv[ni], acc[mi][ni], 0, 0, 0);
        }
    }
  } else {
    // ---- 1-pass, BK=64: plane0 = k..k+31, plane1 = k+32..k+63 ----
    auto stage64 = [&](int k0) {
#pragma unroll
      for (int t = 0; t < 2; ++t) {
        const int c = wave * 2 + t;
        const int row = c * 16 + (lane >> 2);
        const int kc = (lane & 3) * 8;
        const size_t ga = (size_t)(bm + row) * K + k0 + kc;
        const size_t gb = (size_t)(bn + row) * K + k0 + kc;
        gload16(J.Ah + ga, &sA[0][c * 512]);
        gload16(J.Bh + gb, &sB[0][c * 512]);
        gload16(J.Ah + ga + 32, &sA[1][c * 512]);
        gload16(J.Bh + gb + 32, &sB[1][c * 512]);
      }
    };
    stage64(0);
    const int T2 = K / 64;
    for (int t = 0; t < T2; ++t) {
      __syncthreads();                  // DMA(t) complete
      f16x8 a0[4], b0[4];
#pragma unroll
      for (int mi = 0; mi < 4; ++mi) {
        a0[mi] = *(const f16x8*)&sA[0][abase + mi * 512];
        b0[mi] = *(const f16x8*)&sB[0][bbase + mi * 512];
      }
#pragma unroll
      for (int ni = 0; ni < 4; ++ni)
#pragma unroll
        for (int mi = 0; mi < 4; ++mi)
          acc[mi][ni] = __builtin_amdgcn_mfma_f32_16x16x32_f16(a0[mi], b0[ni], acc[mi][ni], 0, 0, 0);
      f16x8 a1[4], b1[4];
#pragma unroll
      for (int mi = 0; mi < 4; ++mi) {
        a1[mi] = *(const f16x8*)&sA[1][abase + mi * 512];
        b1[mi] = *(const f16x8*)&sB[1][bbase + mi * 512];
      }
      __syncthreads();                  // all reads done -> planes free
      if (t + 1 < T2) stage64((t + 1) * 64);  // flies during MFMA1
#pragma unroll
      for (int ni = 0; ni < 4; ++ni)
#pragma unroll
        for (int mi = 0; mi < 4; ++mi)
          acc[mi][ni] = __builtin_amdgcn_mfma_f32_16x16x32_f16(a1[mi], b1[ni], acc[mi][ni], 0, 0, 0);
    }
  }

  // epilogue: C/D layout col=lane&15, row=(lane>>4)*4+reg
  const float sc = 1.f / 4096.f;
#pragma unroll
  for (int ni = 0; ni < 4; ++ni) {
    const int n = bn + wx * 64 + ni * 16 + mr;
    if (n >= J.Nv) continue;
    const float bv = J.bias ? J.bias[n] : 0.f;
#pragma unroll
    for (int mi = 0; mi < 4; ++mi) {
      const int m0 = bm + wy * 64 + mi * 16 + q * 4;
#pragma unroll
      for (int r = 0; r < 4; ++r) {
        const int m = m0 + r;
        float v = acc[mi][ni][r] * sc + bv;
        if (J.act) v = fmaxf(v, 0.f);
        if (J.gum) v += gumbel_for(P.k0, P.k1, (uint32_t)(m * J.ldc + n));
        const size_t off = (size_t)m * J.ldc + n;
        if (J.C) J.C[off] = v;
        if (J.wsplit) {
          const HL s = split64(v);
          J.Ch[off] = s.h;
          J.Cl[off] = s.l;
        }
      }
    }
  }
}

// ---------------- GRU elementwise (step 0 only) + fused h split ----------
__global__ __launch_bounds__(256)
void gru_elem(const float* __restrict__ gi, const float* __restrict__ bhh,
              float* __restrict__ h, _Float16* __restrict__ hh_,
              _Float16* __restrict__ hl_)
{
  const int i = blockIdx.x * 256 + threadIdx.x;
  if (i >= B_ * H_) return;
  const int b = i / H_;
  const int d = i - b * H_;
  const float* gib = gi + (size_t)b * G3_;
  const float ir = gib[d], iz = gib[H_ + d], in_ = gib[2 * H_ + d];
  const float hr = bhh[d], hz = bhh[H_ + d], hn = bhh[2 * H_ + d];
  const float r = 1.f / (1.f + expf(-(ir + hr)));
  const float z = 1.f / (1.f + expf(-(iz + hz)));
  const float n = tanhf(in_ + r * hn);
  const float hv = (1.f - z) * n;      // h_prev = 0
  h[i] = hv;
  const HL s = split64(hv);
  hh_[i] = s.h; hl_[i] = s.l;
}

// ---------------- select + fused GRU for the next step --------------------
__global__ __launch_bounds__(256)
void select_step(const float* __restrict__ v, uint8_t* __restrict__ mask,
                 int* __restrict__ idxs, const float* __restrict__ giCls,
                 const float* __restrict__ AeWih, float* __restrict__ atomp,
                 float* __restrict__ hbuf, const float* __restrict__ WhF,
                 const float* __restrict__ bh, const float* __restrict__ wmaxsq,
                 const float* __restrict__ gh, const float* __restrict__ bhh,
                 _Float16* __restrict__ hh_, _Float16* __restrict__ hl_,
                 uint32_t k0, uint32_t k1, int step)
{
  const int b = blockIdx.x, tid = threadIdx.x;
  uint8_t* mrow = mask + (size_t)b * A_;
  __shared__ float hsh[H_];
  __shared__ float sv[256];
  __shared__ int   si[256];
  __shared__ int   s_list[64];
  __shared__ int   s_n;
  __shared__ int   s_sel;

  // h_j row -> LDS + ||h||^2
  float hp = 0.f;
  for (int d = tid; d < H_; d += 256) {
    const float t = hbuf[(size_t)b * H_ + d];
    hsh[d] = t; hp += t * t;
  }
  sv[tid] = hp; __syncthreads();
  for (int t = 128; t > 0; t >>= 1) {
    if (tid < t) sv[tid] += sv[tid + t];
    __syncthreads();
  }
  const float hn2 = sv[0];
  __syncthreads();

  // mask update
  if (step > 0) {
    const int prev = idxs[(step - 1) * B_ + b];
    if (prev == 0)
      for (int a = tid; a < A_; a += 256) mrow[a] = 0;
    __syncthreads();
    if (tid == 0) mrow[0] = 1;
  }
  if (tid == 0) s_n = 0;
  __syncthreads();

  // pass 1: masked max (no LDS row cache -> high occupancy; rows stay L2-hot)
  const float* vrow = v + (size_t)b * A_;
  float bv = -INFINITY; int bi = A_;
  for (int a = tid; a < A_; a += 256) {
    const float val = mrow[a] ? vrow[a] : -INFINITY;
    if (val > bv) { bv = val; bi = a; }
  }
  sv[tid] = bv; si[tid] = bi; __syncthreads();
  for (int t = 128; t > 0; t >>= 1) {
    if (tid < t) {
      const float v2 = sv[tid + t]; const int i2 = si[tid + t];
      if (v2 > sv[tid] || (v2 == sv[tid] && i2 < si[tid])) { sv[tid] = v2; si[tid] = i2; }
    }
    __syncthreads();
  }
  const float amax = sv[0];
  __syncthreads();

  // |approx-exact| <= 2^-10 * ||h|| * max||w_a||  (x2 safety)
  const float delta = 2.0f * 0.0009765625f * sqrtf(hn2 * wmaxsq[0]);
  const float thr = amax - 2.f * delta;

  // pass 2: candidates (re-read from L2)
  for (int a = tid; a < A_; a += 256)
    if (mrow[a] && vrow[a] >= thr) {
      const int p = atomicAdd(&s_n, 1);
      if (p < 64) s_list[p] = a;
    }
  __syncthreads();
  const int nc = (s_n < 64) ? s_n : 64;

  // exact fp32 re-eval; argmax with lowest-index tie-break
  const uint32_t nbase = (uint32_t)b * (uint32_t)A_;
  float best = -INFINITY; int bestA = A_;
  for (int c = 0; c < nc; ++c) {
    const int a = s_list[c];
    const float* wr = WhF + (size_t)a * H_;
    float p = 0.f;
    for (int d = tid; d < H_; d += 256) p += hsh[d] * wr[d];
    sv[tid] = p; __syncthreads();
    for (int t = 128; t > 0; t >>= 1) {
      if (tid < t) sv[tid] += sv[tid + t];
      __syncthreads();
    }
    if (tid == 0) {
      const float ev = sv[0] + bh[a] + gumbel_for(k0, k1, nbase + (uint32_t)a);
      if (ev > best || (ev == best && a < bestA)) { best = ev; bestA = a; }
    }
    __syncthreads();
  }
  if (tid == 0) {
    s_sel = bestA;
    mrow[bestA] = 0;
    idxs[step * B_ + b] = bestA;
    atomp[(size_t)b * (RL_ * A_) + (size_t)step * A_ + bestA] = 1.0f;
  }
  __syncthreads();

  if (step < RL_ - 1) {
    // gi_{j+1}[d] = giCls[b,d] + AeWih[sel,d]; fused GRU -> h_{j+1}
    const int sel = s_sel;
    const float* ar = AeWih + (size_t)sel * G3_;
    const float* gr = giCls + (size_t)b * G3_;
    const float* ghb = gh + (size_t)b * G3_;
    for (int d = tid; d < H_; d += 256) {
      const float g0 = gr[d] + ar[d];
      const float g1 = gr[H_ + d] + ar[H_ + d];
      const float g2 = gr[2 * H_ + d] + ar[2 * H_ + d];
      const float r = 1.f / (1.f + expf(-(g0 + ghb[d])));
      const float z = 1.f / (1.f + expf(-(g1 + ghb[H_ + d])));
      const float n = tanhf(g2 + r * ghb[2 * H_ + d]);
      const float hv = (1.f - z) * n + z * hsh[d];
      hbuf[(size_t)b * H_ + d] = hv;
      const HL s = split64(hv);
      hh_[(size_t)b * H_ + d] = s.h;
      hl_[(size_t)b * H_ + d] = s.l;
    }
  }
}

// ---------------- final heads ----------------
__global__ __launch_bounds__(256)
void head_k(const int* __restrict__ idxs, const float* __restrict__ ae,
            const float* __restrict__ w_mu, const float* __restrict__ b_mu,
            const float* __restrict__ w_cov, const float* __restrict__ b_cov,
            const float* __restrict__ alpha, float* __restrict__ outf)
{
  const int b = blockIdx.x, tid = threadIdx.x;
  const int i0 = idxs[0 * B_ + b], i1 = idxs[1 * B_ + b];
  const int i2 = idxs[2 * B_ + b], i3 = idxs[3 * B_ + b];
  const float* r0 = ae + (size_t)i0 * H_;
  const float* r1 = ae + (size_t)i1 * H_;
  const float* r2 = ae + (size_t)i2 * H_;
  const float* r3 = ae + (size_t)i3 * H_;
  float pmu = 0.f, pcv = 0.f;
  for (int d = tid; d < H_; d += 256) {
    const float a = r0[d] + r1[d] + r2[d] + r3[d];
    pmu += a * w_mu[d];
    pcv += a * w_cov[d];
  }
  __shared__ float smu[256], scv[256];
  smu[tid] = pmu; scv[tid] = pcv;
  __syncthreads();
  for (int s = 128; s > 0; s >>= 1) {
    if (tid < s) { smu[tid] += smu[tid + s]; scv[tid] += scv[tid + s]; }
    __syncthreads();
  }
  if (tid == 0) {
    const float mu = 1.f / (1.f + expf(-(smu[0] + b_mu[0])));
    const float cv = 1.f / (1.f + expf(-(scv[0] + b_cov[0])));
    const float n = cv * NDATA_;
    const float inv = alpha[0] / n;
    const float pp = (mu + inv) / (1.f + 2.f * inv);
    outf[2 * b + 0] = logf(1.f - pp);
    outf[2 * b + 1] = logf(pp);
    float* cp = outf + 2 * B_ + (size_t)B_ * RL_ * A_;
    cp[2 * b + 0] = 1.f - pp;
    cp[2 * b + 1] = pp;
  }
}

// ---------------- launch ----------------
extern "C" void kernel_launch(void* const* d_in, const int* in_sizes, int n_in,
                              void* d_out, int out_size, void* d_ws, size_t ws_size,
                              hipStream_t stream)
{
  const float* x     = (const float*)d_in[0];
  const int*   xmask = (const int*)d_in[1];
  const float* W1 = (const float*)d_in[2];  const float* b1 = (const float*)d_in[3];
  const float* W2 = (const float*)d_in[4];  const float* b2 = (const float*)d_in[5];
  const float* W3 = (const float*)d_in[6];  const float* b3 = (const float*)d_in[7];
  const float* Wih = (const float*)d_in[8]; const float* bih = (const float*)d_in[9];
  const float* Whh = (const float*)d_in[10];const float* bhh = (const float*)d_in[11];
  const float* Wh = (const float*)d_in[12]; const float* bh = (const float*)d_in[13];
  const float* ae = (const float*)d_in[14];
  const float* w_mu = (const float*)d_in[15];  const float* b_mu = (const float*)d_in[16];
  const float* w_cov = (const float*)d_in[17]; const float* b_cov = (const float*)d_in[18];
  const float* alpha = (const float*)d_in[19];

  char* ws = (char*)d_ws;
  size_t off = 0;
  auto alloc = [&](size_t bytes) -> void* {
    void* p = ws + off;
    off += (bytes + 255) & ~(size_t)255;
    return p;
  };
  float* hbuf   = (float*)alloc((size_t)B_ * H_ * 4);
  float* giCls  = (float*)alloc((size_t)B_ * G3_ * 4);
  float* gh     = (float*)alloc((size_t)B_ * G3_ * 4);
  float* vbuf   = (float*)alloc((size_t)B_ * A_ * 4);
  float* AeWih  = (float*)alloc((size_t)APAD_ * G3_ * 4);
  uint8_t* mask = (uint8_t*)alloc((size_t)B_ * A_);
  int* idxs     = (int*)alloc((size_t)RL_ * B_ * 4);
  _Float16* hh_ = (_Float16*)alloc((size_t)B_ * H_ * 2);
  _Float16* hl_ = (_Float16*)alloc((size_t)B_ * H_ * 2);
  _Float16* xh  = (_Float16*)alloc((size_t)B_ * DIN_ * 2);
  _Float16* xl  = (_Float16*)alloc((size_t)B_ * DIN_ * 2);
  _Float16* t1h = (_Float16*)alloc((size_t)B_ * H_ * 2);
  _Float16* t1l = (_Float16*)alloc((size_t)B_ * H_ * 2);
  _Float16* t2h = (_Float16*)alloc((size_t)B_ * H_ * 2);
  _Float16* t2l = (_Float16*)alloc((size_t)B_ * H_ * 2);
  _Float16* w1h = (_Float16*)alloc((size_t)H_ * DIN_ * 2);
  _Float16* w1l = (_Float16*)alloc((size_t)H_ * DIN_ * 2);
  _Float16* w2h = (_Float16*)alloc((size_t)H_ * H_ * 2);
  _Float16* w2l = (_Float16*)alloc((size_t)H_ * H_ * 2);
  _Float16* w3th = (_Float16*)alloc((size_t)H_ * H_ * 2);   // W3^T split
  _Float16* w3tl = (_Float16*)alloc((size_t)H_ * H_ * 2);
  _Float16* wihh = (_Float16*)alloc((size_t)G3_ * H_ * 2);
  _Float16* wihl = (_Float16*)alloc((size_t)G3_ * H_ * 2);
  _Float16* whhh = (_Float16*)alloc((size_t)G3_ * H_ * 2);
  _Float16* whhl = (_Float16*)alloc((size_t)G3_ * H_ * 2);
  _Float16* whhi = (_Float16*)alloc((size_t)APAD_ * H_ * 2);  // Wh hi (1-pass)
  _Float16* aeh  = (_Float16*)alloc((size_t)APAD_ * H_ * 2);
  _Float16* ael  = (_Float16*)alloc((size_t)APAD_ * H_ * 2);
  _Float16* wph  = (_Float16*)alloc((size_t)G3_ * H_ * 2);    // W' = Wih@W3 split
  _Float16* wpl  = (_Float16*)alloc((size_t)G3_ * H_ * 2);
  float* bprime = (float*)alloc((size_t)G3_ * 4);
  float* wmaxsq = (float*)alloc(4);

  float* outf  = (float*)d_out;
  float* atomp = outf + 2 * B_;

  (void)hipMemsetAsync(d_out, 0, (size_t)out_size * sizeof(float), stream);
  (void)hipMemsetAsync(wmaxsq, 0, 4, stream);

  // merged presplit: W1 W2 W3^T Wih Whh Wh(hi) ae(hi+lo)
  PSJobs J;
  const float* srcs[7] = {W1, W2, W3, Wih, Whh, Wh, ae};
  _Float16* his[7] = {w1h, w2h, w3th, wihh, whhh, whhi, aeh};
  _Float16* los[7] = {w1l, w2l, w3tl, wihl, whhl, nullptr, ael};
  const int Rs[7]    = {H_, H_, H_, G3_, G3_, A_, A_};
  const int Rpads[7] = {H_, H_, H_, G3_, G3_, APAD_, APAD_};
  const int Ks[7]    = {DIN_, H_, H_, H_, H_, H_, H_};
  const int Trs[7]   = {0, 0, 1, 0, 0, 0, 0};
  J.cum[0] = 0;
  for (int j = 0; j < 7; ++j) {
    J.src[j] = srcs[j]; J.hi[j] = his[j]; J.lo[j] = los[j];
    J.R[j] = Rs[j]; J.K[j] = Ks[j]; J.trans[j] = Trs[j];
    J.cum[j + 1] = J.cum[j] + Rpads[j] * Ks[j] / 4;
  }
  presplit_all<<<(J.cum[7] + 255) / 256, 256, 0, stream>>>(J);

  const int XB = (B_ * DIN_ / 4 + 255) / 256;
  prep_k<<<B_ + A_ + XB + G3_, 256, 0, stream>>>(
      xmask, mask, Wh, wmaxsq, x, xh, xl, Wih, b3, bih, bprime);

  auto mkjob = [](const _Float16* Ah, const _Float16* Al, const _Float16* Bh,
                  const _Float16* Bl, const float* bias, float* C,
                  _Float16* Ch, _Float16* Cl, int M, int K, int ldc,
                  int n0, int Nv, int npass, int act, int wsplit, int gum) {
    GJob g; g.Ah = Ah; g.Al = Al; g.Bh = Bh; g.Bl = Bl; g.bias = bias;
    g.C = C; g.Ch = Ch; g.Cl = Cl; g.M = M; g.K = K; g.ldc = ldc;
    g.n0 = n0; g.Nv = Nv; g.npass = npass; g.act = act; g.wsplit = wsplit;
    g.gum = gum;
    return g;
  };
  auto aejob = [&](int t0) {   // AeWih column-chunk job, x-tiles from t0
    return mkjob(aeh, ael, wihh, wihl, nullptr, AeWih, nullptr, nullptr,
                 APAD_, H_, G3_, t0 * 128, G3_, 3, 0, 0, 0);
  };

  // L1: [W1 (x-dep) | W' = Wih@W3^T (weights-only) | AeWih 0..5]
  {
    GArgs P;
    P.j[0] = mkjob(xh, xl, w1h, w1l, b1, nullptr, t1h, t1l,
                   B_, DIN_, H_, 0, H_, 3, 1, 1, 0);
    P.j[1] = mkjob(wihh, wihl, w3th, w3tl, nullptr, nullptr, wph, wpl,
                   G3_, H_, H_, 0, H_, 3, 0, 1, 0);
    P.j[2] = aejob(0);
    P.sx1 = H_ / 128; P.sx2 = H_ / 128 + H_ / 128; P.k0 = 0; P.k1 = 0;
    gemm2job<<<dim3(P.sx2 + 6, APAD_ / 128), 256, 0, stream>>>(P);
  }
  // L2: [W2 | AeWih 6..11]
  {
    GArgs P;
    P.j[0] = mkjob(t1h, t1l, w2h, w2l, b2, nullptr, t2h, t2l,
                   B_, H_, H_, 0, H_, 3, 1, 1, 0);
    P.j[1] = aejob(6);
    P.j[2] = P.j[1];
    P.sx1 = H_ / 128; P.sx2 = H_ / 128 + 6; P.k0 = 0; P.k1 = 0;
    gemm2job<<<dim3(P.sx2, APAD_ / 128), 256, 0, stream>>>(P);
  }
  // L3: [giCls = t2 @ W'^T + b' | AeWih 12..17]
  {
    GArgs P;
    P.j[0] = mkjob(t2h, t2l, wph, wpl, bprime, giCls, nullptr, nullptr,
                   B_, H_, G3_, 0, G3_, 3, 0, 0, 0);
    P.j[1] = aejob(12);
    P.j[2] = P.j[1];
    P.sx1 = G3_ / 128; P.sx2 = G3_ / 128 + 6; P.k0 = 0; P.k1 = 0;
    gemm2job<<<dim3(P.sx2, APAD_ / 128), 256, 0, stream>>>(P);
  }

  uint32_t fk0[RL_], fk1[RL_];
  for (int j = 0; j < RL_; ++j)
    threefry2x32(0u, 42u, 0u, (uint32_t)j, &fk0[j], &fk1[j]);

  // GRU step 0 (gi = giCls, h = 0)
  gru_elem<<<(B_ * H_ + 255) / 256, 256, 0, stream>>>(giCls, bhh, hbuf, hh_, hl_);

  for (int j = 0; j < RL_; ++j) {
    // fused [logits_j (1-pass BK64 + gumbel) | gh_{j+1} (3-pass)] — share h_j
    GArgs P;
    P.j[0] = mkjob(hh_, nullptr, whhi, nullptr, bh, vbuf, nullptr, nullptr,
                   B_, H_, A_, 0, A_, 1, 0, 0, 1);
    const int gx0 = APAD_ / 128;
    int gx = gx0;
    if (j < RL_ - 1) {
      P.j[1] = mkjob(hh_, hl_, whhh, whhl, bhh, gh, nullptr, nullptr,
                     B_, H_, G3_, 0, G3_, 3, 0, 0, 0);
      gx += G3_ / 128;
    } else {
      P.j[1] = P.j[0];
    }
    P.j[2] = P.j[1];
    P.sx1 = gx0; P.sx2 = gx; P.k0 = fk0[j]; P.k1 = fk1[j];
    gemm2job<<<dim3(gx, B_ / 128), 256, 0, stream>>>(P);

    select_step<<<B_, 256, 0, stream>>>(vbuf, mask, idxs, giCls, AeWih, atomp,
                                        hbuf, Wh, bh, wmaxsq, gh, bhh, hh_, hl_,
                                        fk0[j], fk1[j], j);
  }

  head_k<<<B_, 256, 0, stream>>>(idxs, ae, w_mu, b_mu, w_cov, b_cov, alpha, outf);
}

// Round 11
// 932.864 us; speedup vs baseline: 1.6175x; 1.0519x over previous
//
#include <hip/hip_runtime.h>
#include <stdint.h>
#include <math.h>

#define B_    2048
#define DIN_  512
#define H_    768
#define G3_   2304          // 3*H
#define A_    5001
#define APAD_ 5120
#define RL_   4
#define NDATA_ 56000.0f

typedef _Float16 f16x8 __attribute__((ext_vector_type(8)));
typedef _Float16 f16x4 __attribute__((ext_vector_type(4)));
typedef float    f32x4 __attribute__((ext_vector_type(4)));

// ---------------- threefry2x32 (exact JAX semantics) ----------------
__host__ __device__ __forceinline__ void threefry2x32(
    uint32_t k0, uint32_t k1, uint32_t x0, uint32_t x1,
    uint32_t* o0, uint32_t* o1)
{
  const uint32_t ks2 = k0 ^ k1 ^ 0x1BD11BDAu;
#define TF_R(r) { x0 += x1; x1 = (x1 << (r)) | (x1 >> (32 - (r))); x1 ^= x0; }
  x0 += k0; x1 += k1;
  TF_R(13) TF_R(15) TF_R(26) TF_R(6)
  x0 += k1;  x1 += ks2 + 1u;
  TF_R(17) TF_R(29) TF_R(16) TF_R(24)
  x0 += ks2; x1 += k0 + 2u;
  TF_R(13) TF_R(15) TF_R(26) TF_R(6)
  x0 += k0;  x1 += k1 + 3u;
  TF_R(17) TF_R(29) TF_R(16) TF_R(24)
  x0 += k1;  x1 += ks2 + 4u;
  TF_R(13) TF_R(15) TF_R(26) TF_R(6)
  x0 += ks2; x1 += k0 + 5u;
#undef TF_R
  *o0 = x0; *o1 = x1;
}

__device__ __forceinline__ float gumbel_for(uint32_t k0, uint32_t k1, uint32_t n)
{
  uint32_t o0, o1;
  threefry2x32(k0, k1, 0u, n, &o0, &o1);
  const uint32_t bits = o0 ^ o1;
  const float f = __uint_as_float((bits >> 9) | 0x3f800000u);  // [1,2)
  const float minv = 1e-6f;
  const float maxv = 1.0f - 1e-6f;
  const float span = maxv - minv;
  float u = __fmul_rn(f, span);
  u = __fadd_rn(u, minv);
  u = __fsub_rn(u, span);
  u = fmaxf(minv, u);
  return -logf(-logf(u));
}

// split v*64 into f16 hi/lo
struct HL { _Float16 h, l; };
__device__ __forceinline__ HL split64(float v)
{
  HL r;
  const float s = v * 64.f;
  r.h = (_Float16)s;
  r.l = (_Float16)(s - (float)r.h);
  return r;
}

// order-preserving float->uint encoding for atomicMax
__device__ __forceinline__ uint32_t encmax(float f)
{
  const uint32_t b = __float_as_uint(f);
  return (b & 0x80000000u) ? ~b : (b | 0x80000000u);
}
__device__ __forceinline__ float decmax(uint32_t u)
{
  const uint32_t b = (u & 0x80000000u) ? (u & 0x7FFFFFFFu) : ~u;
  return __uint_as_float(b);
}

// async global->LDS, 16 B/lane; LDS dst = wave-uniform base + lane*16
__device__ __forceinline__ void gload16(const void* g, void* l)
{
  __builtin_amdgcn_global_load_lds(
      (const __attribute__((address_space(1))) void*)g,
      (__attribute__((address_space(3))) void*)l, 16, 0, 0);
}

// ---------------- merged pre-split of 7 weight tensors (opt transpose) -----
struct PSJobs {
  const float* src[7];
  _Float16* hi[7];
  _Float16* lo[7];
  int R[7]; int K[7]; int trans[7];   // trans: out[r][k] = src[k*R + r]
  int cum[8];          // cumulative float4 counts
};

__global__ __launch_bounds__(256)
void presplit_all(PSJobs J)
{
  const int g = blockIdx.x * 256 + threadIdx.x;
  if (g >= J.cum[7]) return;
  int j = 0;
  while (g >= J.cum[j + 1]) ++j;
  const int i = g - J.cum[j];
  const int K = J.K[j];
  const int e = i * 4;
  const int row = e / K;
  const int col = e - row * K;
  float4 f = make_float4(0.f, 0.f, 0.f, 0.f);
  if (J.trans[j]) {
    const int R = J.R[j];
    f.x = J.src[j][(size_t)(col + 0) * R + row];
    f.y = J.src[j][(size_t)(col + 1) * R + row];
    f.z = J.src[j][(size_t)(col + 2) * R + row];
    f.w = J.src[j][(size_t)(col + 3) * R + row];
  } else if (row < J.R[j]) {
    f = *(const float4*)(J.src[j] + (size_t)row * K + col);
  }
  const HL s0 = split64(f.x), s1 = split64(f.y);
  const HL s2 = split64(f.z), s3 = split64(f.w);
  const f16x4 hv = {s0.h, s1.h, s2.h, s3.h};
  ((f16x4*)J.hi[j])[i] = hv;
  if (J.lo[j]) {
    const f16x4 lv = {s0.l, s1.l, s2.l, s3.l};
    ((f16x4*)J.lo[j])[i] = lv;
  }
}

// ------- prep: mask init + max||Wh_a||^2 + x split + b' = Wih@b3 + bih -----
__global__ __launch_bounds__(256)
void prep_k(const int* __restrict__ xmask, uint8_t* __restrict__ mask,
            const float* __restrict__ Wh, float* __restrict__ wmaxsq,
            const float* __restrict__ x, _Float16* __restrict__ xh,
            _Float16* __restrict__ xl, const float* __restrict__ Wih,
            const float* __restrict__ b3, const float* __restrict__ bih,
            float* __restrict__ bprime)
{
  const int blk = blockIdx.x, tid = threadIdx.x;
  const int XB = (B_ * DIN_ / 4 + 255) / 256;
  __shared__ float redf[256];
  __shared__ int   redi[256];
  if (blk < B_) {                       // mask init (+ step-0 row_zero fix)
    const int b = blk;
    int s = 0;
    for (int a = tid; a < A_; a += 256) {
      const int m = (xmask[(size_t)b * A_ + a] != 0) ? 1 : 0;
      mask[(size_t)b * A_ + a] = (uint8_t)m;
      s += m;
    }
    redi[tid] = s; __syncthreads();
    for (int t = 128; t > 0; t >>= 1) {
      if (tid < t) redi[tid] += redi[tid + t];
      __syncthreads();
    }
    if (tid == 0 && redi[0] == 0) mask[(size_t)b * A_] = 1;
  } else if (blk < B_ + A_) {           // max row-norm^2 of Wh
    const int a = blk - B_;
    float p = 0.f;
    for (int d = tid; d < H_; d += 256) {
      const float w = Wh[(size_t)a * H_ + d];
      p += w * w;
    }
    redf[tid] = p; __syncthreads();
    for (int t = 128; t > 0; t >>= 1) {
      if (tid < t) redf[tid] += redf[tid + t];
      __syncthreads();
    }
    if (tid == 0) atomicMax((int*)wmaxsq, __float_as_int(redf[0]));
  } else if (blk < B_ + A_ + XB) {      // split x
    const int i = (blk - B_ - A_) * 256 + tid;
    const int n4 = B_ * DIN_ / 4;
    if (i < n4) {
      const float4 f = ((const float4*)x)[i];
      const HL s0 = split64(f.x), s1 = split64(f.y);
      const HL s2 = split64(f.z), s3 = split64(f.w);
      const f16x4 hv = {s0.h, s1.h, s2.h, s3.h};
      const f16x4 lv = {s0.l, s1.l, s2.l, s3.l};
      ((f16x4*)xh)[i] = hv;
      ((f16x4*)xl)[i] = lv;
    }
  } else {                              // b'[n] = Wih[n,:]@b3 + bih[n]
    const int n = blk - B_ - A_ - XB;
    float p = 0.f;
    for (int d = tid; d < H_; d += 256)
      p += Wih[(size_t)n * H_ + d] * b3[d];
    redf[tid] = p; __syncthreads();
    for (int t = 128; t > 0; t >>= 1) {
      if (tid < t) redf[tid] += redf[tid + t];
      __syncthreads();
    }
    if (tid == 0) bprime[n] = redf[0] + bih[n];
  }
}

// ================= generic 3-job f16-split MFMA GEMM =================
// Grid: blockIdx.x = row-block (L2 locality: consecutive blocks share the
// B column tile), blockIdx.y = column/job index.
// gum job: stores masked v (+gumbel), -inf for masked; per-row max fused
// into the epilogue via LDS reduce + global atomicMax (encmax encoding).
struct GJob {
  const _Float16 *Ah, *Al, *Bh, *Bl;
  const float* bias;
  float* C;
  _Float16 *Ch, *Cl;
  const uint8_t* mask;     // gum only
  uint32_t* rowmax;        // gum only
  int M, K, ldc, n0, Nv;
  int npass, act, wsplit, gum;
};
struct GArgs { GJob j[3]; int sx1, sx2; uint32_t k0, k1; };

__global__ __launch_bounds__(256)
void gemm2job(GArgs P)
{
  __shared__ _Float16 sA[2][128 * 32];
  __shared__ _Float16 sB[2][128 * 32];

  const int by = blockIdx.y;
  const int jid = (by < P.sx1) ? 0 : ((by < P.sx2) ? 1 : 2);
  const GJob J = P.j[jid];
  const int bxx = by - ((jid == 0) ? 0 : ((jid == 1) ? P.sx1 : P.sx2));
  const int bm = blockIdx.x * 128;
  if (bm >= J.M) return;
  const int bn = J.n0 + bxx * 128;

  const int tid = threadIdx.x;
  const int lane = tid & 63, wave = tid >> 6;
  const int wx = wave & 1, wy = wave >> 1;
  const int q = lane >> 4, mr = lane & 15;
  const int K = J.K;
  const int np3 = (J.npass == 3);

  f32x4 acc[4][4];
#pragma unroll
  for (int i = 0; i < 4; ++i)
#pragma unroll
    for (int j = 0; j < 4; ++j) acc[i][j] = (f32x4)0.f;

  const int abase = (wy * 64 + mr) * 32 + q * 8;
  const int bbase = (wx * 64 + mr) * 32 + q * 8;

  if (np3) {
    // ---- 3-pass, BK=32: plane0 = hi, plane1 = lo ----
    auto stage = [&](int k0) {
#pragma unroll
      for (int t = 0; t < 2; ++t) {
        const int c = wave * 2 + t;               // chunk: 16 rows x 32 f16
        const int row = c * 16 + (lane >> 2);
        const int kc = (lane & 3) * 8;
        const size_t ga = (size_t)(bm + row) * K + k0 + kc;
        const size_t gb = (size_t)(bn + row) * K + k0 + kc;
        gload16(J.Ah + ga, &sA[0][c * 512]);
        gload16(J.Bh + gb, &sB[0][c * 512]);
        gload16(J.Al + ga, &sA[1][c * 512]);
        gload16(J.Bl + gb, &sB[1][c * 512]);
      }
    };
    stage(0);
    const int T = K / 32;
    for (int t = 0; t < T; ++t) {
      __syncthreads();                  // DMA(t) complete
      f16x8 ah[4], al[4], bhv[4], blv[4];
#pragma unroll
      for (int mi = 0; mi < 4; ++mi) {
        ah[mi]  = *(const f16x8*)&sA[0][abase + mi * 512];
        bhv[mi] = *(const f16x8*)&sB[0][bbase + mi * 512];
        al[mi]  = *(const f16x8*)&sA[1][abase + mi * 512];
        blv[mi] = *(const f16x8*)&sB[1][bbase + mi * 512];
      }
      __syncthreads();                  // reads done -> buffers free
      if (t + 1 < T) stage((t + 1) * 32);
#pragma unroll
      for (int ni = 0; ni < 4; ++ni)
#pragma unroll
        for (int mi = 0; mi < 4; ++mi) {
          acc[mi][ni] = __builtin_amdgcn_mfma_f32_16x16x32_f16(ah[mi], bhv[ni], acc[mi][ni], 0, 0, 0);
          acc[mi][ni] = __builtin_amdgcn_mfma_f32_16x16x32_f16(al[mi], bhv[ni], acc[mi][ni], 0, 0, 0);
          acc[mi][ni] = __builtin_amdgcn_mfma_f32_16x16x32_f16(ah[mi], blv[ni], acc[mi][ni], 0, 0, 0);
        }
    }
  } else {
    // ---- 1-pass, BK=64: plane0 = k..k+31, plane1 = k+32..k+63 ----
    auto stage64 = [&](int k0) {
#pragma unroll
      for (int t = 0; t < 2; ++t) {
        const int c = wave * 2 + t;
        const int row = c * 16 + (lane >> 2);
        const int kc = (lane & 3) * 8;
        const size_t ga = (size_t)(bm + row) * K + k0 + kc;
        const size_t gb = (size_t)(bn + row) * K + k0 + kc;
        gload16(J.Ah + ga, &sA[0][c * 512]);
        gload16(J.Bh + gb, &sB[0][c * 512]);
        gload16(J.Ah + ga + 32, &sA[1][c * 512]);
        gload16(J.Bh + gb + 32, &sB[1][c * 512]);
      }
    };
    stage64(0);
    const int T2 = K / 64;
    for (int t = 0; t < T2; ++t) {
      __syncthreads();                  // DMA(t) complete
      f16x8 a0[4], b0[4];
#pragma unroll
      for (int mi = 0; mi < 4; ++mi) {
        a0[mi] = *(const f16x8*)&sA[0][abase + mi * 512];
        b0[mi] = *(const f16x8*)&sB[0][bbase + mi * 512];
      }
#pragma unroll
      for (int ni = 0; ni < 4; ++ni)
#pragma unroll
        for (int mi = 0; mi < 4; ++mi)
          acc[mi][ni] = __builtin_amdgcn_mfma_f32_16x16x32_f16(a0[mi], b0[ni], acc[mi][ni], 0, 0, 0);
      f16x8 a1[4], b1[4];
#pragma unroll
      for (int mi = 0; mi < 4; ++mi) {
        a1[mi] = *(const f16x8*)&sA[1][abase + mi * 512];
        b1[mi] = *(const f16x8*)&sB[1][bbase + mi * 512];
      }
      __syncthreads();                  // all reads done -> planes free
      if (t + 1 < T2) stage64((t + 1) * 64);  // flies during MFMA1
#pragma unroll
      for (int ni = 0; ni < 4; ++ni)
#pragma unroll
        for (int mi = 0; mi < 4; ++mi)
          acc[mi][ni] = __builtin_amdgcn_mfma_f32_16x16x32_f16(a1[mi], b1[ni], acc[mi][ni], 0, 0, 0);
    }
  }

  // epilogue: C/D layout col=lane&15, row=(lane>>4)*4+reg
  const float sc = 1.f / 4096.f;
  float lm[4][4];                      // per-row local max (gum)
#pragma unroll
  for (int mi = 0; mi < 4; ++mi)
#pragma unroll
    for (int r = 0; r < 4; ++r) lm[mi][r] = -INFINITY;

#pragma unroll
  for (int ni = 0; ni < 4; ++ni) {
    const int n = bn + wx * 64 + ni * 16 + mr;
    if (n >= J.Nv) continue;
    const float bv = J.bias ? J.bias[n] : 0.f;
#pragma unroll
    for (int mi = 0; mi < 4; ++mi) {
      const int m0 = bm + wy * 64 + mi * 16 + q * 4;
#pragma unroll
      for (int r = 0; r < 4; ++r) {
        const int m = m0 + r;
        float v = acc[mi][ni][r] * sc + bv;
        if (J.act) v = fmaxf(v, 0.f);
        const size_t off = (size_t)m * J.ldc + n;
        if (J.gum) {
          v += gumbel_for(P.k0, P.k1, (uint32_t)(m * J.ldc + n));
          const bool ok = J.mask[off] != 0;
          if (ok && v > lm[mi][r]) lm[mi][r] = v;
          J.C[off] = ok ? v : -INFINITY;
        } else {
          if (J.C) J.C[off] = v;
        }
        if (J.wsplit) {
          const HL s = split64(v);
          J.Ch[off] = s.h;
          J.Cl[off] = s.l;
        }
      }
    }
  }

  if (J.gum) {
    // per-row max over the 128-row block: LDS reduce then 1 atomic/row
    uint32_t* rmx = (uint32_t*)&sA[0][0];
    __syncthreads();
    if (tid < 128) rmx[tid] = 0u;
    __syncthreads();
#pragma unroll
    for (int mi = 0; mi < 4; ++mi)
#pragma unroll
      for (int r = 0; r < 4; ++r)
        atomicMax(&rmx[wy * 64 + mi * 16 + q * 4 + r], encmax(lm[mi][r]));
    __syncthreads();
    if (tid < 128) atomicMax(J.rowmax + bm + tid, rmx[tid]);
  }
}

// ------- GRU elementwise (step 0 only) + fused h split + rowmax reset ------
__global__ __launch_bounds__(256)
void gru_elem(const float* __restrict__ gi, const float* __restrict__ bhh,
              float* __restrict__ h, _Float16* __restrict__ hh_,
              _Float16* __restrict__ hl_, uint32_t* __restrict__ rowmax)
{
  const int i = blockIdx.x * 256 + threadIdx.x;
  if (i >= B_ * H_) return;
  const int b = i / H_;
  const int d = i - b * H_;
  if (d == 0) rowmax[b] = 0u;          // reset for step-0 GEMM
  const float* gib = gi + (size_t)b * G3_;
  const float ir = gib[d], iz = gib[H_ + d], in_ = gib[2 * H_ + d];
  const float hr = bhh[d], hz = bhh[H_ + d], hn = bhh[2 * H_ + d];
  const float r = 1.f / (1.f + expf(-(ir + hr)));
  const float z = 1.f / (1.f + expf(-(iz + hz)));
  const float n = tanhf(in_ + r * hn);
  const float hv = (1.f - z) * n;      // h_prev = 0
  h[i] = hv;
  const HL s = split64(hv);
  hh_[i] = s.h; hl_[i] = s.l;
}

// ---------------- select (amax pre-computed) + fused GRU + mask pre-update -
__global__ __launch_bounds__(256)
void select_step(const float* __restrict__ v, uint8_t* __restrict__ mask,
                 int* __restrict__ idxs, const float* __restrict__ giCls,
                 const float* __restrict__ AeWih, float* __restrict__ atomp,
                 float* __restrict__ hbuf, const float* __restrict__ WhF,
                 const float* __restrict__ bh, const float* __restrict__ wmaxsq,
                 const float* __restrict__ gh, const float* __restrict__ bhh,
                 _Float16* __restrict__ hh_, _Float16* __restrict__ hl_,
                 uint32_t* __restrict__ rowmax,
                 uint32_t k0, uint32_t k1, int step)
{
  const int b = blockIdx.x, tid = threadIdx.x;
  uint8_t* mrow = mask + (size_t)b * A_;
  __shared__ float hsh[H_];
  __shared__ float sv[256];
  __shared__ int   s_list[64];
  __shared__ int   s_n;
  __shared__ int   s_sel;

  // h_j row -> LDS + ||h||^2
  float hp = 0.f;
  for (int d = tid; d < H_; d += 256) {
    const float t = hbuf[(size_t)b * H_ + d];
    hsh[d] = t; hp += t * t;
  }
  sv[tid] = hp;
  if (tid == 0) s_n = 0;
  __syncthreads();
  for (int t = 128; t > 0; t >>= 1) {
    if (tid < t) sv[tid] += sv[tid + t];
    __syncthreads();
  }
  const float hn2 = sv[0];
  __syncthreads();

  // amax from the GEMM-epilogue fused rowmax
  const float amax = decmax(rowmax[b]);
  const float delta = 2.0f * 0.0009765625f * sqrtf(hn2 * wmaxsq[0]);
  const float thr = amax - 2.f * delta;

  // candidates (vbuf already masked: -inf where disallowed)
  const float* vrow = v + (size_t)b * A_;
  for (int a = tid; a < A_; a += 256)
    if (vrow[a] >= thr) {
      const int p = atomicAdd(&s_n, 1);
      if (p < 64) s_list[p] = a;
    }
  __syncthreads();
  const int nc = (s_n < 64) ? s_n : 64;

  // exact fp32 re-eval; argmax with lowest-index tie-break
  const uint32_t nbase = (uint32_t)b * (uint32_t)A_;
  float best = -INFINITY; int bestA = A_;
  for (int c = 0; c < nc; ++c) {
    const int a = s_list[c];
    const float* wr = WhF + (size_t)a * H_;
    float p = 0.f;
    for (int d = tid; d < H_; d += 256) p += hsh[d] * wr[d];
    sv[tid] = p; __syncthreads();
    for (int t = 128; t > 0; t >>= 1) {
      if (tid < t) sv[tid] += sv[tid + t];
      __syncthreads();
    }
    if (tid == 0) {
      const float ev = sv[0] + bh[a] + gumbel_for(k0, k1, nbase + (uint32_t)a);
      if (ev > best || (ev == best && a < bestA)) { best = ev; bestA = a; }
    }
    __syncthreads();
  }
  if (tid == 0) {
    s_sel = bestA;
    idxs[step * B_ + b] = bestA;
    atomp[(size_t)b * (RL_ * A_) + (size_t)step * A_ + bestA] = 1.0f;
  }
  __syncthreads();
  const int sel = s_sel;

  if (step < RL_ - 1) {
    // mask pre-update for step j+1: clear sel; if sel==0 clear row; mrow[0]=1
    if (sel == 0) {
      for (int a = tid; a < A_; a += 256) mrow[a] = 0;
    }
    __syncthreads();
    if (tid == 0) {
      if (sel != 0) mrow[sel] = 0;
      mrow[0] = 1;
      rowmax[b] = 0u;                  // reset for next step's GEMM
    }
    // gi_{j+1}[d] = giCls[b,d] + AeWih[sel,d]; fused GRU -> h_{j+1}
    const float* ar = AeWih + (size_t)sel * G3_;
    const float* gr = giCls + (size_t)b * G3_;
    const float* ghb = gh + (size_t)b * G3_;
    for (int d = tid; d < H_; d += 256) {
      const float g0 = gr[d] + ar[d];
      const float g1 = gr[H_ + d] + ar[H_ + d];
      const float g2 = gr[2 * H_ + d] + ar[2 * H_ + d];
      const float r = 1.f / (1.f + expf(-(g0 + ghb[d])));
      const float z = 1.f / (1.f + expf(-(g1 + ghb[H_ + d])));
      const float n = tanhf(g2 + r * ghb[2 * H_ + d]);
      const float hv = (1.f - z) * n + z * hsh[d];
      hbuf[(size_t)b * H_ + d] = hv;
      const HL s = split64(hv);
      hh_[(size_t)b * H_ + d] = s.h;
      hl_[(size_t)b * H_ + d] = s.l;
    }
  }
}

// ---------------- final heads ----------------
__global__ __launch_bounds__(256)
void head_k(const int* __restrict__ idxs, const float* __restrict__ ae,
            const float* __restrict__ w_mu, const float* __restrict__ b_mu,
            const float* __restrict__ w_cov, const float* __restrict__ b_cov,
            const float* __restrict__ alpha, float* __restrict__ outf)
{
  const int b = blockIdx.x, tid = threadIdx.x;
  const int i0 = idxs[0 * B_ + b], i1 = idxs[1 * B_ + b];
  const int i2 = idxs[2 * B_ + b], i3 = idxs[3 * B_ + b];
  const float* r0 = ae + (size_t)i0 * H_;
  const float* r1 = ae + (size_t)i1 * H_;
  const float* r2 = ae + (size_t)i2 * H_;
  const float* r3 = ae + (size_t)i3 * H_;
  float pmu = 0.f, pcv = 0.f;
  for (int d = tid; d < H_; d += 256) {
    const float a = r0[d] + r1[d] + r2[d] + r3[d];
    pmu += a * w_mu[d];
    pcv += a * w_cov[d];
  }
  __shared__ float smu[256], scv[256];
  smu[tid] = pmu; scv[tid] = pcv;
  __syncthreads();
  for (int s = 128; s > 0; s >>= 1) {
    if (tid < s) { smu[tid] += smu[tid + s]; scv[tid] += scv[tid + s]; }
    __syncthreads();
  }
  if (tid == 0) {
    const float mu = 1.f / (1.f + expf(-(smu[0] + b_mu[0])));
    const float cv = 1.f / (1.f + expf(-(scv[0] + b_cov[0])));
    const float n = cv * NDATA_;
    const float inv = alpha[0] / n;
    const float pp = (mu + inv) / (1.f + 2.f * inv);
    outf[2 * b + 0] = logf(1.f - pp);
    outf[2 * b + 1] = logf(pp);
    float* cp = outf + 2 * B_ + (size_t)B_ * RL_ * A_;
    cp[2 * b + 0] = 1.f - pp;
    cp[2 * b + 1] = pp;
  }
}

// ---------------- launch ----------------
extern "C" void kernel_launch(void* const* d_in, const int* in_sizes, int n_in,
                              void* d_out, int out_size, void* d_ws, size_t ws_size,
                              hipStream_t stream)
{
  const float* x     = (const float*)d_in[0];
  const int*   xmask = (const int*)d_in[1];
  const float* W1 = (const float*)d_in[2];  const float* b1 = (const float*)d_in[3];
  const float* W2 = (const float*)d_in[4];  const float* b2 = (const float*)d_in[5];
  const float* W3 = (const float*)d_in[6];  const float* b3 = (const float*)d_in[7];
  const float* Wih = (const float*)d_in[8]; const float* bih = (const float*)d_in[9];
  const float* Whh = (const float*)d_in[10];const float* bhh = (const float*)d_in[11];
  const float* Wh = (const float*)d_in[12]; const float* bh = (const float*)d_in[13];
  const float* ae = (const float*)d_in[14];
  const float* w_mu = (const float*)d_in[15];  const float* b_mu = (const float*)d_in[16];
  const float* w_cov = (const float*)d_in[17]; const float* b_cov = (const float*)d_in[18];
  const float* alpha = (const float*)d_in[19];

  char* ws = (char*)d_ws;
  size_t off = 0;
  auto alloc = [&](size_t bytes) -> void* {
    void* p = ws + off;
    off += (bytes + 255) & ~(size_t)255;
    return p;
  };
  float* hbuf   = (float*)alloc((size_t)B_ * H_ * 4);
  float* giCls  = (float*)alloc((size_t)B_ * G3_ * 4);
  float* gh     = (float*)alloc((size_t)B_ * G3_ * 4);
  float* vbuf   = (float*)alloc((size_t)B_ * A_ * 4);
  float* AeWih  = (float*)alloc((size_t)APAD_ * G3_ * 4);
  uint8_t* mask = (uint8_t*)alloc((size_t)B_ * A_);
  int* idxs     = (int*)alloc((size_t)RL_ * B_ * 4);
  uint32_t* rowmax = (uint32_t*)alloc((size_t)B_ * 4);
  _Float16* hh_ = (_Float16*)alloc((size_t)B_ * H_ * 2);
  _Float16* hl_ = (_Float16*)alloc((size_t)B_ * H_ * 2);
  _Float16* xh  = (_Float16*)alloc((size_t)B_ * DIN_ * 2);
  _Float16* xl  = (_Float16*)alloc((size_t)B_ * DIN_ * 2);
  _Float16* t1h = (_Float16*)alloc((size_t)B_ * H_ * 2);
  _Float16* t1l = (_Float16*)alloc((size_t)B_ * H_ * 2);
  _Float16* t2h = (_Float16*)alloc((size_t)B_ * H_ * 2);
  _Float16* t2l = (_Float16*)alloc((size_t)B_ * H_ * 2);
  _Float16* w1h = (_Float16*)alloc((size_t)H_ * DIN_ * 2);
  _Float16* w1l = (_Float16*)alloc((size_t)H_ * DIN_ * 2);
  _Float16* w2h = (_Float16*)alloc((size_t)H_ * H_ * 2);
  _Float16* w2l = (_Float16*)alloc((size_t)H_ * H_ * 2);
  _Float16* w3th = (_Float16*)alloc((size_t)H_ * H_ * 2);   // W3^T split
  _Float16* w3tl = (_Float16*)alloc((size_t)H_ * H_ * 2);
  _Float16* wihh = (_Float16*)alloc((size_t)G3_ * H_ * 2);
  _Float16* wihl = (_Float16*)alloc((size_t)G3_ * H_ * 2);
  _Float16* whhh = (_Float16*)alloc((size_t)G3_ * H_ * 2);
  _Float16* whhl = (_Float16*)alloc((size_t)G3_ * H_ * 2);
  _Float16* whhi = (_Float16*)alloc((size_t)APAD_ * H_ * 2);  // Wh hi (1-pass)
  _Float16* aeh  = (_Float16*)alloc((size_t)APAD_ * H_ * 2);
  _Float16* ael  = (_Float16*)alloc((size_t)APAD_ * H_ * 2);
  _Float16* wph  = (_Float16*)alloc((size_t)G3_ * H_ * 2);    // W' = Wih@W3 split
  _Float16* wpl  = (_Float16*)alloc((size_t)G3_ * H_ * 2);
  float* bprime = (float*)alloc((size_t)G3_ * 4);
  float* wmaxsq = (float*)alloc(4);

  float* outf  = (float*)d_out;
  float* atomp = outf + 2 * B_;

  (void)hipMemsetAsync(d_out, 0, (size_t)out_size * sizeof(float), stream);
  (void)hipMemsetAsync(wmaxsq, 0, 4, stream);

  // merged presplit: W1 W2 W3^T Wih Whh Wh(hi) ae(hi+lo)
  PSJobs J;
  const float* srcs[7] = {W1, W2, W3, Wih, Whh, Wh, ae};
  _Float16* his[7] = {w1h, w2h, w3th, wihh, whhh, whhi, aeh};
  _Float16* los[7] = {w1l, w2l, w3tl, wihl, whhl, nullptr, ael};
  const int Rs[7]    = {H_, H_, H_, G3_, G3_, A_, A_};
  const int Rpads[7] = {H_, H_, H_, G3_, G3_, APAD_, APAD_};
  const int Ks[7]    = {DIN_, H_, H_, H_, H_, H_, H_};
  const int Trs[7]   = {0, 0, 1, 0, 0, 0, 0};
  J.cum[0] = 0;
  for (int j = 0; j < 7; ++j) {
    J.src[j] = srcs[j]; J.hi[j] = his[j]; J.lo[j] = los[j];
    J.R[j] = Rs[j]; J.K[j] = Ks[j]; J.trans[j] = Trs[j];
    J.cum[j + 1] = J.cum[j] + Rpads[j] * Ks[j] / 4;
  }
  presplit_all<<<(J.cum[7] + 255) / 256, 256, 0, stream>>>(J);

  const int XB = (B_ * DIN_ / 4 + 255) / 256;
  prep_k<<<B_ + A_ + XB + G3_, 256, 0, stream>>>(
      xmask, mask, Wh, wmaxsq, x, xh, xl, Wih, b3, bih, bprime);

  auto mkjob = [](const _Float16* Ah, const _Float16* Al, const _Float16* Bh,
                  const _Float16* Bl, const float* bias, float* C,
                  _Float16* Ch, _Float16* Cl, int M, int K, int ldc,
                  int n0, int Nv, int npass, int act, int wsplit, int gum) {
    GJob g; g.Ah = Ah; g.Al = Al; g.Bh = Bh; g.Bl = Bl; g.bias = bias;
    g.C = C; g.Ch = Ch; g.Cl = Cl; g.mask = nullptr; g.rowmax = nullptr;
    g.M = M; g.K = K; g.ldc = ldc;
    g.n0 = n0; g.Nv = Nv; g.npass = npass; g.act = act; g.wsplit = wsplit;
    g.gum = gum;
    return g;
  };
  auto aejob = [&](int t0) {   // AeWih column-chunk job, col-tiles from t0
    return mkjob(aeh, ael, wihh, wihl, nullptr, AeWih, nullptr, nullptr,
                 APAD_, H_, G3_, t0 * 128, G3_, 3, 0, 0, 0);
  };

  // L1: [W1 (x-dep) | W' = Wih@W3^T (weights-only) | AeWih 0..5]
  {
    GArgs P;
    P.j[0] = mkjob(xh, xl, w1h, w1l, b1, nullptr, t1h, t1l,
                   B_, DIN_, H_, 0, H_, 3, 1, 1, 0);
    P.j[1] = mkjob(wihh, wihl, w3th, w3tl, nullptr, nullptr, wph, wpl,
                   G3_, H_, H_, 0, H_, 3, 0, 1, 0);
    P.j[2] = aejob(0);
    P.sx1 = H_ / 128; P.sx2 = H_ / 128 + H_ / 128; P.k0 = 0; P.k1 = 0;
    gemm2job<<<dim3(APAD_ / 128, P.sx2 + 6), 256, 0, stream>>>(P);
  }
  // L2: [W2 | AeWih 6..11]
  {
    GArgs P;
    P.j[0] = mkjob(t1h, t1l, w2h, w2l, b2, nullptr, t2h, t2l,
                   B_, H_, H_, 0, H_, 3, 1, 1, 0);
    P.j[1] = aejob(6);
    P.j[2] = P.j[1];
    P.sx1 = H_ / 128; P.sx2 = H_ / 128 + 6; P.k0 = 0; P.k1 = 0;
    gemm2job<<<dim3(APAD_ / 128, P.sx2), 256, 0, stream>>>(P);
  }
  // L3: [giCls = t2 @ W'^T + b' | AeWih 12..17]
  {
    GArgs P;
    P.j[0] = mkjob(t2h, t2l, wph, wpl, bprime, giCls, nullptr, nullptr,
                   B_, H_, G3_, 0, G3_, 3, 0, 0, 0);
    P.j[1] = aejob(12);
    P.j[2] = P.j[1];
    P.sx1 = G3_ / 128; P.sx2 = G3_ / 128 + 6; P.k0 = 0; P.k1 = 0;
    gemm2job<<<dim3(APAD_ / 128, P.sx2), 256, 0, stream>>>(P);
  }

  uint32_t fk0[RL_], fk1[RL_];
  for (int j = 0; j < RL_; ++j)
    threefry2x32(0u, 42u, 0u, (uint32_t)j, &fk0[j], &fk1[j]);

  // GRU step 0 (gi = giCls, h = 0) + rowmax reset
  gru_elem<<<(B_ * H_ + 255) / 256, 256, 0, stream>>>(giCls, bhh, hbuf, hh_,
                                                      hl_, rowmax);

  for (int j = 0; j < RL_; ++j) {
    // fused [logits_j (1-pass BK64 + gumbel + rowmax) | gh_{j+1} (3-pass)]
    GArgs P;
    P.j[0] = mkjob(hh_, nullptr, whhi, nullptr, bh, vbuf, nullptr, nullptr,
                   B_, H_, A_, 0, A_, 1, 0, 0, 1);
    P.j[0].mask = mask; P.j[0].rowmax = rowmax;
    const int gx0 = APAD_ / 128;
    int gx = gx0;
    if (j < RL_ - 1) {
      P.j[1] = mkjob(hh_, hl_, whhh, whhl, bhh, gh, nullptr, nullptr,
                     B_, H_, G3_, 0, G3_, 3, 0, 0, 0);
      gx += G3_ / 128;
    } else {
      P.j[1] = P.j[0];
    }
    P.j[2] = P.j[1];
    P.sx1 = gx0; P.sx2 = gx; P.k0 = fk0[j]; P.k1 = fk1[j];
    gemm2job<<<dim3(B_ / 128, gx), 256, 0, stream>>>(P);

    select_step<<<B_, 256, 0, stream>>>(vbuf, mask, idxs, giCls, AeWih, atomp,
                                        hbuf, Wh, bh, wmaxsq, gh, bhh, hh_, hl_,
                                        rowmax, fk0[j], fk1[j], j);
  }

  head_k<<<B_, 256, 0, stream>>>(idxs, ae, w_mu, b_mu, w_cov, b_cov, alpha, outf);
}